// Round 10
// baseline (568.917 us; speedup 1.0000x reference)
//
#include <hip/hip_runtime.h>
#include <hip/hip_bf16.h>
#include <cstdint>
#include <cstddef>

#define KS 5
#define K3 125

typedef __attribute__((ext_vector_type(8))) short bf16x8;
typedef __attribute__((ext_vector_type(4))) float f32x4;

struct CsrArgs {
    const int* dst[5];
    int* deg[5];
    int* elist[5];
    int E[5];
    int N[5];
};
struct WtArgs {
    const float* W[5];
    unsigned short* Wt[5];
    int Kd[5], KdP[5], Co[5];
};
struct ScanTbl {
    int degOff[24]; int rpOff[24]; int curOff[24]; int cnt[24];
    int lfirst[6];
    int rpNOff[5]; int Eval[5];
};

__device__ __forceinline__ unsigned f2ord(float f){
    unsigned u = __float_as_uint(f);
    return (u & 0x80000000u) ? ~u : (u | 0x80000000u);
}
__device__ __forceinline__ float ord2f(unsigned u){
    unsigned b = (u & 0x80000000u) ? (u & 0x7FFFFFFFu) : ~u;
    return __uint_as_float(b);
}
__device__ __forceinline__ unsigned short f2bf(float f){
    unsigned u = __float_as_uint(f);
    u = (u + 0x7FFFu + ((u >> 16) & 1u)) >> 16;
    return (unsigned short)u;
}
__device__ __forceinline__ unsigned pk_bf16(float a, float b){
    __hip_bfloat162 p = __float22bfloat162_rn(make_float2(a, b));
    return *(unsigned*)&p;
}

// ---------------- degree histogram (all layers) ----------------
__global__ void k_deg_all(CsrArgs a){
    int l = blockIdx.y;
    int e = blockIdx.x*blockDim.x + threadIdx.x;
    if(e < a.E[l]) atomicAdd(&a.deg[l][a.dst[l][e]], 1);
}

// ---------------- hierarchical scan ----------------
__global__ __launch_bounds__(256) void k_scanA(ScanTbl t, const int* __restrict__ deg_a,
        int* __restrict__ rowp_a, int* __restrict__ bsum){
    __shared__ int part[256];
    int b = blockIdx.x;
    int n = t.cnt[b];
    const int* d = deg_a + t.degOff[b];
    int* rp = rowp_a + t.rpOff[b];
    int tid = threadIdx.x;
    int v[16]; int s = 0;
    #pragma unroll
    for(int j=0;j<16;j++){
        int idx = tid*16 + j;
        v[j] = (idx < n) ? d[idx] : 0;
        s += v[j];
    }
    part[tid] = s;
    __syncthreads();
    #pragma unroll
    for(int off=1; off<256; off<<=1){
        int val = (tid >= off) ? part[tid-off] : 0;
        __syncthreads();
        part[tid] += val;
        __syncthreads();
    }
    int run = tid ? part[tid-1] : 0;
    #pragma unroll
    for(int j=0;j<16;j++){
        int idx = tid*16 + j;
        if(idx < n){ rp[idx] = run; run += v[j]; }
    }
    if(tid == 255) bsum[b] = part[255];
}
__global__ void k_scanB(ScanTbl t, int* __restrict__ bsum, int* __restrict__ rowp_a){
    int l = threadIdx.x;
    if(l < 5){
        int run = 0;
        for(int b=t.lfirst[l]; b<t.lfirst[l+1]; b++){
            int tmp = bsum[b]; bsum[b] = run; run += tmp;
        }
        rowp_a[t.rpNOff[l]] = t.Eval[l];
    }
}
__global__ __launch_bounds__(256) void k_scanC(ScanTbl t, int* __restrict__ rowp_a,
        const int* __restrict__ bsum, int* __restrict__ curs_a){
    int b = blockIdx.x;
    int n = t.cnt[b];
    int off = bsum[b];
    int* rp = rowp_a + t.rpOff[b];
    int* cu = curs_a + t.curOff[b];
    for(int idx=threadIdx.x; idx<n; idx+=256){
        int val = rp[idx] + off;
        rp[idx] = val;
        cu[idx] = val;
    }
}

// ---------------- CSR fill (all layers) ----------------
__global__ void k_fill_all2(CsrArgs a, int* curs0, int* curs1, int* curs2, int* curs3, int* curs4){
    int l = blockIdx.y;
    int* curs = (l==0)?curs0:(l==1)?curs1:(l==2)?curs2:(l==3)?curs3:curs4;
    int e = blockIdx.x*blockDim.x + threadIdx.x;
    if(e < a.E[l]){
        int p = atomicAdd(&curs[a.dst[l][e]], 1);
        a.elist[l][p] = e;
    }
}

// ---------------- fused W transpose+bf16 ----------------
__global__ __launch_bounds__(256) void k_wt_all(WtArgs a){
    int l = blockIdx.z;
    int Kd = a.Kd[l], KdP = a.KdP[l], Co = a.Co[l];
    int kb = blockIdx.x*64, cb = blockIdx.y*64;
    if(kb >= KdP || cb >= Co) return;
    const float* W = a.W[l];
    unsigned short* Wt = a.Wt[l];
    __shared__ float t[64][65];
    int tid = threadIdx.x;
    int cc = tid & 63, rg = tid >> 6;
    #pragma unroll
    for(int i=0;i<16;i++){
        int kl = rg + i*4;
        int kk = kb + kl, co = cb + cc;
        t[kl][cc] = (kk < Kd && co < Co) ? W[(size_t)kk*Co + co] : 0.f;
    }
    __syncthreads();
    int kl = tid & 63;
    #pragma unroll
    for(int i=0;i<16;i++){
        int col = rg + i*4;
        int co = cb + col;
        int kk = kb + kl;
        if(co < Co && kk < KdP) Wt[(size_t)co*KdP + kk] = f2bf(t[kl][col]);
    }
}

// ---------------- spline basis helper ----------------
__device__ __forceinline__ void spline_meta(float dx, float dy, float dz, float inv2r,
        float* wgt, int* ki){
    float fr[3]; int k0[3];
    float dd[3] = {dx, dy, dz};
    #pragma unroll
    for(int dim=0; dim<3; dim++){
        float p = dd[dim]*inv2r + 0.5f;
        p = fminf(fmaxf(p, 0.f), 1.f);
        float u = p*4.0f;
        float kf = fminf(floorf(u), 3.f);
        fr[dim] = u - kf; k0[dim] = (int)kf;
    }
    #pragma unroll
    for(int bits=0; bits<8; bits++){
        wgt[bits] = ((bits&1)? fr[0] : 1.f-fr[0])
                  * ((bits&2)? fr[1] : 1.f-fr[1])
                  * ((bits&4)? fr[2] : 1.f-fr[2]);
        ki[bits]  = (k0[0]+(bits&1)) + KS*(k0[1]+((bits>>1)&1)) + KS*KS*(k0[2]+((bits>>2)&1));
    }
}

// ---------------- build A, 32-ci-slice per block, atomic-free buckets ----------------
__global__ __launch_bounds__(256) void k_build2(const int* __restrict__ src,
        const float* __restrict__ pos, const float* __restrict__ x,
        const int* __restrict__ rowptr, const int* __restrict__ elist,
        float inv2r, int n0, int Cin, int KdP, unsigned short* __restrict__ A){
    const int CH = 32, BK = 64;
    __shared__ float row[K3*32];
    __shared__ float xbuf[CH*32];
    __shared__ float ew[CH][8];
    __shared__ unsigned short bkt[8][BK];
    __shared__ int bcnt[8];
    __shared__ int esrc[CH];
    int tid = threadIdx.x;
    int node = n0 + blockIdx.x;
    int ci0 = blockIdx.y*32;
    for(int i=tid; i<K3*32; i+=256) row[i] = 0.f;
    int e0 = rowptr[node], e1 = rowptr[node+1];
    float pdx = pos[node*3+0], pdy = pos[node*3+1], pdz = pos[node*3+2];

    for(int c0=e0; c0<e1; c0+=CH){
        int cnt = min(CH, e1-c0);
        __syncthreads();
        if(tid < 8) bcnt[tid] = 0;
        float w[8]; int ki[8];
        if(tid < cnt){
            int e = elist[c0+tid];
            int s = src[e];
            esrc[tid] = s;
            spline_meta(pdx-pos[s*3+0], pdy-pos[s*3+1], pdz-pos[s*3+2], inv2r, w, ki);
            #pragma unroll
            for(int b=0;b<8;b++) ew[tid][b] = w[b];
        }
        __syncthreads();
        if(tid < cnt){
            #pragma unroll
            for(int b=0;b<8;b++){
                int g = ki[b] & 7;
                int p = atomicAdd(&bcnt[g], 1);
                bkt[g][p] = (unsigned short)((ki[b]<<8) | (tid<<3) | b);
            }
        }
        for(int i=tid; i<cnt*32; i+=256){
            int e = i >> 5, ci = i & 31;
            xbuf[i] = x[(size_t)esrc[e]*Cin + ci0 + ci];
        }
        __syncthreads();
        int g  = tid >> 5;
        int cl = tid & 31;
        int ng = bcnt[g];
        for(int i=0; i<ng; i++){
            unsigned v = bkt[g][i];
            int kq = v >> 8;
            int e  = (v >> 3) & 31;
            float wv = ew[e][v & 7];
            row[kq*32 + cl] += wv * xbuf[e*32 + cl];
        }
    }
    __syncthreads();
    size_t gbase = (size_t)blockIdx.x*KdP + ci0;
    for(int i=tid*4; i<K3*32; i+=1024){
        int k = i >> 5, c = i & 31;
        uint2 pk;
        pk.x = pk_bf16(row[i],   row[i+1]);
        pk.y = pk_bf16(row[i+2], row[i+3]);
        *(uint2*)&A[gbase + (size_t)k*Cin + c] = pk;
    }
}

// ---------------- build for Cin==1 (layer 1) ----------------
__global__ __launch_bounds__(256) void k_build1(const int* __restrict__ src,
        const float* __restrict__ pos, const float* __restrict__ x,
        const int* __restrict__ rowptr, const int* __restrict__ elist,
        float inv2r, int n0, int KdP, unsigned short* __restrict__ A){
    const int NB = 32, KD = K3;
    __shared__ float rows[NB*KD];
    int tid = threadIdx.x;
    for(int i=tid; i<NB*KD; i+=256) rows[i] = 0.f;
    __syncthreads();
    int nb = tid >> 3;
    int grp = tid & 7;
    int node = n0 + blockIdx.x*NB + nb;
    float* row = rows + nb*KD;
    float pdx = pos[node*3+0], pdy = pos[node*3+1], pdz = pos[node*3+2];
    int e0 = rowptr[node], e1 = rowptr[node+1];
    for(int ii=e0+grp; ii<e1; ii+=8){
        int e = elist[ii];
        int s = src[e];
        float w[8]; int ki[8];
        spline_meta(pdx-pos[s*3+0], pdy-pos[s*3+1], pdz-pos[s*3+2], inv2r, w, ki);
        float xs = x[s];
        #pragma unroll
        for(int b=0; b<8; b++)
            __hip_atomic_fetch_add(&row[ki[b]], w[b]*xs, __ATOMIC_RELAXED, __HIP_MEMORY_SCOPE_WORKGROUP);
    }
    __syncthreads();
    size_t gbase = (size_t)blockIdx.x*NB*KdP;
    int tot = NB*KdP;
    for(int i=tid*2; i<tot; i+=512){
        int nbw = i / KdP;
        int kk  = i - nbw*KdP;
        float v0 = (kk   < KD) ? rows[nbw*KD + kk]   : 0.f;
        float v1 = (kk+1 < KD) ? rows[nbw*KD + kk+1] : 0.f;
        *(unsigned*)&A[gbase + i] = pk_bf16(v0, v1);
    }
}

// ---------------- MFMA GEMM (BN in {32,64,96,128}) ----------------
template<int BN>
__global__ __launch_bounds__(256) void k_mfma(const unsigned short* __restrict__ A,
        const unsigned short* __restrict__ Wt, float* __restrict__ acc,
        int n0, int Co, int KdP, int Kper){
    const int NBF = BN/16;
    __shared__ unsigned short Al[128*32];
    __shared__ unsigned short Bl[BN*32];
    int tid = threadIdx.x;
    int m0 = blockIdx.x*128, nb0 = blockIdx.y*BN;
    int kstart = blockIdx.z*Kper;
    int kend = min(KdP, kstart + Kper);
    if(kstart >= kend) return;
    int w = tid >> 6, l = tid & 63, lm = l & 15, lk = l >> 4;
    f32x4 c[2][NBF];
    #pragma unroll
    for(int i=0;i<2;i++)
        #pragma unroll
        for(int j=0;j<NBF;j++) c[i][j] = (f32x4){0,0,0,0};
    int ar = tid >> 1, ah = (tid & 1)*16;

    for(int k0=kstart; k0<kend; k0+=32){
        const unsigned short* ga = A + (size_t)(m0+ar)*KdP + k0 + ah;
        *(uint4*)&Al[ar*32 + ah]     = *(const uint4*)ga;
        *(uint4*)&Al[ar*32 + ah + 8] = *(const uint4*)(ga + 8);
        #pragma unroll
        for(int i=tid; i<BN*4; i+=256){
            int bn = i >> 2, bk = (i & 3)*8;
            *(uint4*)&Bl[bn*32 + bk] = *(const uint4*)(Wt + (size_t)(nb0+bn)*KdP + k0 + bk);
        }
        __syncthreads();
        bf16x8 af[2], bfr[NBF];
        #pragma unroll
        for(int i=0;i<2;i++) af[i] = *(bf16x8*)&Al[(w*32 + i*16 + lm)*32 + lk*8];
        #pragma unroll
        for(int j=0;j<NBF;j++) bfr[j] = *(bf16x8*)&Bl[(j*16 + lm)*32 + lk*8];
        #pragma unroll
        for(int i=0;i<2;i++)
            #pragma unroll
            for(int j=0;j<NBF;j++)
                c[i][j] = __builtin_amdgcn_mfma_f32_16x16x32_bf16(af[i], bfr[j], c[i][j], 0,0,0);
        __syncthreads();
    }
    #pragma unroll
    for(int i=0;i<2;i++){
        int mb = n0 + m0 + w*32 + i*16 + lk*4;
        #pragma unroll
        for(int j=0;j<NBF;j++){
            int col = nb0 + j*16 + lm;
            if(gridDim.z == 1){
                #pragma unroll
                for(int r=0;r<4;r++) acc[(size_t)(mb+r)*Co + col] = c[i][j][r];
            } else {
                #pragma unroll
                for(int r=0;r<4;r++) atomicAdd(&acc[(size_t)(mb+r)*Co + col], c[i][j][r]);
            }
        }
    }
}

// ---------------- conv epilogue + fused attention-pool atomics ----------------
__global__ void k_finish2(const float* __restrict__ acc, const int* __restrict__ deg,
        const float* __restrict__ xin, const float* __restrict__ root,
        const float* __restrict__ bias, const float* __restrict__ Wa,
        const float* __restrict__ ba, float* __restrict__ y,
        const int* __restrict__ cl, const float* __restrict__ pin,
        unsigned long long* __restrict__ m_p, float* __restrict__ cntf,
        float* __restrict__ ppos, int N, int Cin, int Co, int NPB){
    extern __shared__ float sm[];
    float* xs  = sm;
    float* red = sm + NPB*Cin;
    int tid = threadIdx.x;
    int nl = tid / Co, co = tid - nl*Co;
    int n = blockIdx.x*NPB + nl;
    bool act = (n < N);
    if(act) for(int c=co; c<Cin; c+=Co) xs[nl*Cin + c] = xin[(size_t)n*Cin + c];
    __syncthreads();
    float yv = 0.f;
    if(act){
        float v = acc[(size_t)n*Co + co] / (float)max(deg[n], 1);
        float rt = 0.f;
        for(int c=0; c<Cin; c++) rt += xs[nl*Cin + c]*root[(size_t)c*Co + co];
        v += rt + bias[co];
        yv = v > 0.f ? v : expm1f(v);
        y[(size_t)n*Co + co] = yv;
    }
    if(m_p){
        float av = act ? yv * Wa[co*2] : 0.f;
        if(Co <= 64){
            #pragma unroll
            for(int off=32; off>0; off>>=1)
                if(off < Co) av += __shfl_xor(av, off, 64);
        } else {
            red[tid] = av;
            __syncthreads();
            int cur = Co;
            while(cur > 1){
                int half = (cur+1) >> 1;
                if(co < cur-half) red[nl*Co+co] += red[nl*Co+co+half];
                __syncthreads();
                cur = half;
            }
            av = red[nl*Co];
        }
        if(act && co==0){
            float attv = av + ba[0];
            int c = cl[n];
            unsigned long long pk = ((unsigned long long)f2ord(attv) << 32) | (unsigned)(~n);
            atomicMax(&m_p[c], pk);
            atomicAdd(&cntf[c], 1.f);
            atomicAdd(&ppos[c*3+0], pin[n*3+0]);
            atomicAdd(&ppos[c*3+1], pin[n*3+1]);
            atomicAdd(&ppos[c*3+2], pin[n*3+2]);
        }
    }
}

// ---------------- pool gather ----------------
__global__ void k_pool3(const unsigned long long* __restrict__ m_p, const float* __restrict__ cntf,
        const float* __restrict__ ppos, const float* __restrict__ x,
        float* __restrict__ xo, float* __restrict__ poso, int nc, int Co, int nmax){
    int t = blockIdx.x*blockDim.x + threadIdx.x;
    if(t >= nc*Co) return;
    int c = t / Co;
    int co = t - c*Co;
    unsigned s = ~(unsigned)(m_p[c] & 0xFFFFFFFFull);
    s = min(s, (unsigned)(nmax-1));
    xo[(size_t)c*Co + co] = x[(size_t)s*Co + co];
    if(co < 3) poso[c*3+co] = ppos[c*3+co] / fmaxf(cntf[c], 1.f);
}

// ---------------- final voxel max pool ----------------
__global__ void k_vox(const float* __restrict__ x, const float* __restrict__ pos,
        unsigned* __restrict__ mx_u, float* __restrict__ cnt8){
    int nidx = blockIdx.x, ch = threadIdx.x;
    int v0 = min(max((int)floorf(pos[nidx*3+0]+0.5f),0),1);
    int v1 = min(max((int)floorf(pos[nidx*3+1]+0.5f),0),1);
    int v2 = min(max((int)floorf(pos[nidx*3+2]+0.5f),0),1);
    int b = nidx >> 3;
    int cl = b*8 + v0*4 + v1*2 + v2;
    atomicMax(&mx_u[cl*256+ch], f2ord(x[nidx*256+ch]));
    if(ch==0) atomicAdd(&cnt8[cl], 1.f);
}

// ---------------- FC + log_softmax ----------------
__global__ __launch_bounds__(256) void k_fc(const unsigned* __restrict__ mx_u,
        const float* __restrict__ cnt8, const float* __restrict__ Wfc,
        const float* __restrict__ bfc, float* __restrict__ out){
    __shared__ float sred[10][256];
    int b = blockIdx.x, tid = threadIdx.x;
    float p[10];
    #pragma unroll
    for(int j=0;j<10;j++) p[j]=0.f;
    for(int idx=tid; idx<2048; idx+=256){
        int v = idx >> 8;
        float val = (cnt8[b*8+v] > 0.f) ? ord2f(mx_u[b*2048+idx]) : 0.f;
        const float* wr = &Wfc[idx*10];
        #pragma unroll
        for(int j=0;j<10;j++) p[j] += val*wr[j];
    }
    #pragma unroll
    for(int j=0;j<10;j++) sred[j][tid]=p[j];
    __syncthreads();
    for(int s=128;s>0;s>>=1){
        if(tid<s){
            #pragma unroll
            for(int j=0;j<10;j++) sred[j][tid]+=sred[j][tid+s];
        }
        __syncthreads();
    }
    if(tid==0){
        float lg[10], mx=-1e30f, se=0.f;
        for(int j=0;j<10;j++){ lg[j]=sred[j][0]+bfc[j]; mx=fmaxf(mx,lg[j]); }
        for(int j=0;j<10;j++) se += expf(lg[j]-mx);
        float lse = mx + logf(se);
        for(int j=0;j<10;j++) out[b*10+j] = lg[j]-lse;
    }
}

extern "C" void kernel_launch(void* const* d_in, const int* in_sizes, int n_in,
                              void* d_out, int out_size, void* d_ws, size_t ws_size,
                              hipStream_t stream){
    const float* x0   = (const float*)d_in[0];
    const float* pos0 = (const float*)d_in[1];
    const float *Wc[5], *rootc[5], *bc[5];
    for(int i=0;i<5;i++){
        Wc[i]    = (const float*)d_in[2+3*i];
        rootc[i] = (const float*)d_in[3+3*i];
        bc[i]    = (const float*)d_in[4+3*i];
    }
    const float *Wa[4], *ba[4];
    for(int i=0;i<4;i++){
        Wa[i] = (const float*)d_in[17+2*i];
        ba[i] = (const float*)d_in[18+2*i];
    }
    const float* Wfc = (const float*)d_in[25];
    const float* bfc = (const float*)d_in[26];
    const int* ei[5]; for(int i=0;i<5;i++) ei[i] = (const int*)d_in[27+i];
    const int* cl[4]; for(int i=0;i<4;i++) cl[i] = (const int*)d_in[32+i];

    const int NPG[5]   = {2048,512,128,32,8};
    const int chans[6] = {1,32,64,96,128,256};
    const float inv2r[5] = {5.f,5.f,4.f,2.f,1.f};
    const int B = 32;
    int Ns[5], Es[5], KdPs[5];
    int totN=0, totE=0, totWt=0, accTot=0, poolTot=0;
    int nodeBase[5], edgeBase[5], wtBase[5], accOff[5], poolOff[4];
    for(int l=0;l<5;l++){
        Ns[l] = B*NPG[l]; Es[l] = Ns[l]*16;
        int Kd = K3*chans[l];
        KdPs[l] = (Kd + 31) & ~31;
        nodeBase[l] = totN; totN += Ns[l];
        edgeBase[l] = totE; totE += Es[l];
        wtBase[l] = totWt; totWt += chans[l+1]*KdPs[l];
        accOff[l] = accTot; accTot += Ns[l]*chans[l+1];
    }
    for(int l=0;l<4;l++){ poolOff[l] = poolTot; poolTot += Ns[l+1]; }

    size_t off = 0;
    auto alloc = [&](size_t bytes)->void*{
        void* p = (char*)d_ws + off;
        off = (off + bytes + 255) & ~(size_t)255;
        return p;
    };
    // ---- non-zeroed region ----
    float*    x_a    = (float*)   alloc((size_t)65536*32*4);
    float*    x_b    = (float*)   alloc((size_t)16384*32*4);
    float*    pos_a  = (float*)   alloc((size_t)16384*3*4);
    float*    pos_b  = (float*)   alloc((size_t)4096*3*4);
    int*      rowp_a = (int*)     alloc((size_t)(totN+5)*4);
    int*      curs_a = (int*)     alloc((size_t)totN*4);
    int*      elist_a= (int*)     alloc((size_t)totE*4);
    int*      bsum   = (int*)     alloc((size_t)32*4);
    unsigned short* Wt_a = (unsigned short*)alloc((size_t)totWt*2);
    // ---- zero region (single memset) ----
    size_t zstart = off;
    int*      deg_a  = (int*)     alloc((size_t)totN*4);
    float*    acc_a  = (float*)   alloc((size_t)accTot*4);
    unsigned long long* m_p_a = (unsigned long long*)alloc((size_t)poolTot*8);
    float*    cntf_a = (float*)   alloc((size_t)poolTot*4);
    float*    ppos_a = (float*)   alloc((size_t)poolTot*12);
    unsigned* mx_u   = (unsigned*)alloc((size_t)256*256*4);
    float*    cnt8   = (float*)   alloc((size_t)256*4);
    size_t zlen = off - zstart;
    // ---- A tail ----
    unsigned short* A = (unsigned short*)((char*)d_ws + off);
    size_t Abudget = (ws_size > off) ? (ws_size - off) : 0;

    CsrArgs ca; WtArgs wa;
    for(int l=0;l<5;l++){
        ca.dst[l] = ei[l] + Es[l];
        ca.deg[l] = deg_a + nodeBase[l];
        ca.elist[l] = elist_a + edgeBase[l];
        ca.E[l] = Es[l]; ca.N[l] = Ns[l];
        wa.W[l] = Wc[l]; wa.Wt[l] = Wt_a + wtBase[l];
        wa.Kd[l] = K3*chans[l]; wa.KdP[l] = KdPs[l]; wa.Co[l] = chans[l+1];
    }

    ScanTbl st;
    int nblk = 0;
    for(int l=0;l<5;l++){
        st.lfirst[l] = nblk;
        for(int ls=0; ls<Ns[l]; ls+=4096){
            st.degOff[nblk] = nodeBase[l] + ls;
            st.rpOff[nblk]  = nodeBase[l] + l + ls;
            st.curOff[nblk] = nodeBase[l] + ls;
            st.cnt[nblk]    = (Ns[l]-ls < 4096) ? (Ns[l]-ls) : 4096;
            nblk++;
        }
        st.rpNOff[l] = nodeBase[l] + l + Ns[l];
        st.Eval[l]   = Es[l];
    }
    st.lfirst[5] = nblk;

    hipMemsetAsync((char*)d_ws + zstart, 0, zlen, stream);
    k_deg_all<<<dim3(4096,5), 256, 0, stream>>>(ca);
    k_scanA<<<nblk, 256, 0, stream>>>(st, deg_a, rowp_a, bsum);
    k_scanB<<<1, 64, 0, stream>>>(st, bsum, rowp_a);
    k_scanC<<<nblk, 256, 0, stream>>>(st, rowp_a, bsum, curs_a);
    k_fill_all2<<<dim3(4096,5), 256, 0, stream>>>(ca, curs_a+nodeBase[0], curs_a+nodeBase[1],
        curs_a+nodeBase[2], curs_a+nodeBase[3], curs_a+nodeBase[4]);
    k_wt_all<<<dim3(250,4,5), 256, 0, stream>>>(wa);

    const float* xin = x0;
    const float* pin = pos0;

    for(int L=0; L<5; L++){
        int N  = Ns[L];
        int Cin = chans[L], Co = chans[L+1];
        int KdP = KdPs[L];
        const int* srcp = ei[L];
        const int* rowptrL = rowp_a + nodeBase[L] + L;
        const int* elistL  = ca.elist[L];
        const unsigned short* WtL = wa.Wt[L];
        const int* degL = ca.deg[L];
        float* accL = acc_a + accOff[L];

        size_t nodeb = (size_t)KdP*2;
        int Mc = (int)(Abudget / nodeb);
        Mc = (Mc / 128) * 128;
        if(Mc < 128) Mc = 128;
        if(Mc > N) Mc = N;

        for(int rn0=0; rn0<N; rn0+=Mc){
            int rn1 = (rn0+Mc < N) ? rn0+Mc : N;
            int Mr  = rn1 - rn0;
            if(Cin==1)
                k_build1<<<Mr/32, 256, 0, stream>>>(srcp, pin, xin, rowptrL, elistL, inv2r[L], rn0, KdP, A);
            else
                k_build2<<<dim3(Mr, Cin/32), 256, 0, stream>>>(srcp, pin, xin, rowptrL, elistL,
                                                               inv2r[L], rn0, Cin, KdP, A);

            int BN = (Co%128==0)?128:(Co%96==0)?96:(Co%64==0)?64:32;
            int gx = Mr/128, gy = Co/BN;
            int S = 512/(gx*gy);
            if(S < 1) S = 1;
            if(S > 64) S = 64;
            int maxS = KdP/32;
            if(S > maxS) S = maxS;
            int Kper = ((KdP + S - 1)/S + 31) & ~31;
            S = (KdP + Kper - 1)/Kper;
            dim3 g(gx, gy, S);
            if(BN == 128)      k_mfma<128><<<g, 256, 0, stream>>>(A, WtL, accL, rn0, Co, KdP, Kper);
            else if(BN == 96)  k_mfma<96> <<<g, 256, 0, stream>>>(A, WtL, accL, rn0, Co, KdP, Kper);
            else if(BN == 64)  k_mfma<64> <<<g, 256, 0, stream>>>(A, WtL, accL, rn0, Co, KdP, Kper);
            else               k_mfma<32> <<<g, 256, 0, stream>>>(A, WtL, accL, rn0, Co, KdP, Kper);
        }

        float* y = x_a;
        int NPB = 256/Co; if(NPB < 1) NPB = 1;
        int thr = NPB*Co;
        size_t smb = (size_t)(NPB*Cin + NPB*Co)*4;
        bool haspool = (L < 4);
        k_finish2<<<(N+NPB-1)/NPB, thr, smb, stream>>>(accL, degL, xin, rootc[L], bc[L],
            haspool?Wa[L]:nullptr, haspool?ba[L]:nullptr, y,
            haspool?cl[L]:nullptr, pin,
            haspool?(m_p_a+poolOff[L]):nullptr,
            haspool?(cntf_a+poolOff[L]):nullptr,
            haspool?(ppos_a+(size_t)poolOff[L]*3):nullptr,
            N, Cin, Co, NPB);

        if(haspool){
            int nc = Ns[L+1];
            float* pout = (L%2==0) ? pos_a : pos_b;
            k_pool3<<<(nc*Co+255)/256, 256, 0, stream>>>(m_p_a+poolOff[L], cntf_a+poolOff[L],
                ppos_a+(size_t)poolOff[L]*3, y, x_b, pout, nc, Co, N);
            xin = x_b; pin = pout;
        }
    }

    k_vox<<<256, 256, 0, stream>>>(x_a, pin, mx_u, cnt8);
    k_fc<<<32, 256, 0, stream>>>(mx_u, cnt8, Wfc, bfc, (float*)d_out);
}

// Round 11
// 545.014 us; speedup vs baseline: 1.0439x; 1.0439x over previous
//
#include <hip/hip_runtime.h>
#include <hip/hip_bf16.h>
#include <cstdint>
#include <cstddef>

#define KS 5
#define K3 125

typedef __attribute__((ext_vector_type(8))) short bf16x8;
typedef __attribute__((ext_vector_type(4))) float f32x4;

struct CsrArgs {
    const int* dst[5];
    int* deg[5];
    int* elist[5];
    int E[5];
    int N[5];
};
struct WtArgs {
    const float* W[5];
    unsigned short* Wt[5];
    int Kd[5], KdP[5], Co[5];
};
struct ScanTbl {
    int degOff[24]; int rpOff[24]; int curOff[24]; int cnt[24];
    int lfirst[6];
    int rpNOff[5]; int Eval[5];
};

__device__ __forceinline__ unsigned f2ord(float f){
    unsigned u = __float_as_uint(f);
    return (u & 0x80000000u) ? ~u : (u | 0x80000000u);
}
__device__ __forceinline__ float ord2f(unsigned u){
    unsigned b = (u & 0x80000000u) ? (u & 0x7FFFFFFFu) : ~u;
    return __uint_as_float(b);
}
__device__ __forceinline__ unsigned short f2bf(float f){
    unsigned u = __float_as_uint(f);
    u = (u + 0x7FFFu + ((u >> 16) & 1u)) >> 16;
    return (unsigned short)u;
}
__device__ __forceinline__ unsigned pk_bf16(float a, float b){
    __hip_bfloat162 p = __float22bfloat162_rn(make_float2(a, b));
    return *(unsigned*)&p;
}

// ---------------- fused preamble: degree histogram + W transpose/convert ----------------
// blocks [0, 20480): deg for layer b/4096 ; blocks [20480, 25480): wt tiles
__global__ __launch_bounds__(256) void k_pre(CsrArgs ca, WtArgs wa){
    __shared__ float t[64][65];
    int b = blockIdx.x;
    int tid = threadIdx.x;
    if(b < 20480){
        int l = b >> 12;            // /4096
        int bx = b & 4095;
        int e = bx*256 + tid;
        if(e < ca.E[l]) atomicAdd(&ca.deg[l][ca.dst[l][e]], 1);
        return;
    }
    int r = b - 20480;              // 0..4999
    int l = r / 1000;
    int rr = r - l*1000;
    int kb = (rr % 250)*64;
    int cb = (rr / 250)*64;
    int Kd = wa.Kd[l], KdP = wa.KdP[l], Co = wa.Co[l];
    if(kb >= KdP || cb >= Co) return;
    const float* W = wa.W[l];
    unsigned short* Wt = wa.Wt[l];
    int cc = tid & 63, rg = tid >> 6;
    #pragma unroll
    for(int i=0;i<16;i++){
        int kl = rg + i*4;
        int kk = kb + kl, co = cb + cc;
        t[kl][cc] = (kk < Kd && co < Co) ? W[(size_t)kk*Co + co] : 0.f;
    }
    __syncthreads();
    int kl = tid & 63;
    #pragma unroll
    for(int i=0;i<16;i++){
        int col = rg + i*4;
        int co = cb + col;
        int kk = kb + kl;
        if(co < Co && kk < KdP) Wt[(size_t)co*KdP + kk] = f2bf(t[kl][col]);
    }
}

// ---------------- hierarchical scan (A: per-block scan; C: apply layer prefix) ----------------
__global__ __launch_bounds__(256) void k_scanA(ScanTbl t, const int* __restrict__ deg_a,
        int* __restrict__ rowp_a, int* __restrict__ bsum){
    __shared__ int part[256];
    int b = blockIdx.x;
    int n = t.cnt[b];
    const int* d = deg_a + t.degOff[b];
    int* rp = rowp_a + t.rpOff[b];
    int tid = threadIdx.x;
    int v[16]; int s = 0;
    #pragma unroll
    for(int j=0;j<16;j++){
        int idx = tid*16 + j;
        v[j] = (idx < n) ? d[idx] : 0;
        s += v[j];
    }
    part[tid] = s;
    __syncthreads();
    #pragma unroll
    for(int off=1; off<256; off<<=1){
        int val = (tid >= off) ? part[tid-off] : 0;
        __syncthreads();
        part[tid] += val;
        __syncthreads();
    }
    int run = tid ? part[tid-1] : 0;
    #pragma unroll
    for(int j=0;j<16;j++){
        int idx = tid*16 + j;
        if(idx < n){ rp[idx] = run; run += v[j]; }
    }
    if(tid == 255) bsum[b] = part[255];
}
__global__ __launch_bounds__(256) void k_scanC(ScanTbl t, int* __restrict__ rowp_a,
        const int* __restrict__ bsum, int* __restrict__ curs_a){
    __shared__ int soff;
    int b = blockIdx.x;
    int tid = threadIdx.x;
    int l = 0;
    while(b >= t.lfirst[l+1]) l++;
    if(tid == 0){
        int o = 0;
        for(int i=t.lfirst[l]; i<b; i++) o += bsum[i];
        soff = o;
        if(b == t.lfirst[l]) rowp_a[t.rpNOff[l]] = t.Eval[l];
    }
    __syncthreads();
    int n = t.cnt[b];
    int off = soff;
    int* rp = rowp_a + t.rpOff[b];
    int* cu = curs_a + t.curOff[b];
    for(int idx=tid; idx<n; idx+=256){
        int val = rp[idx] + off;
        rp[idx] = val;
        cu[idx] = val;
    }
}

// ---------------- CSR fill (all layers) ----------------
__global__ void k_fill_all2(CsrArgs a, int* curs0, int* curs1, int* curs2, int* curs3, int* curs4){
    int l = blockIdx.y;
    int* curs = (l==0)?curs0:(l==1)?curs1:(l==2)?curs2:(l==3)?curs3:curs4;
    int e = blockIdx.x*blockDim.x + threadIdx.x;
    if(e < a.E[l]){
        int p = atomicAdd(&curs[a.dst[l][e]], 1);
        a.elist[l][p] = e;
    }
}

// ---------------- spline basis helper ----------------
__device__ __forceinline__ void spline_meta(float dx, float dy, float dz, float inv2r,
        float* wgt, int* ki){
    float fr[3]; int k0[3];
    float dd[3] = {dx, dy, dz};
    #pragma unroll
    for(int dim=0; dim<3; dim++){
        float p = dd[dim]*inv2r + 0.5f;
        p = fminf(fmaxf(p, 0.f), 1.f);
        float u = p*4.0f;
        float kf = fminf(floorf(u), 3.f);
        fr[dim] = u - kf; k0[dim] = (int)kf;
    }
    #pragma unroll
    for(int bits=0; bits<8; bits++){
        wgt[bits] = ((bits&1)? fr[0] : 1.f-fr[0])
                  * ((bits&2)? fr[1] : 1.f-fr[1])
                  * ((bits&4)? fr[2] : 1.f-fr[2]);
        ki[bits]  = (k0[0]+(bits&1)) + KS*(k0[1]+((bits>>1)&1)) + KS*KS*(k0[2]+((bits>>2)&1));
    }
}

// ---------------- build A, 32-ci-slice per block, atomic-free buckets ----------------
__global__ __launch_bounds__(256) void k_build2(const int* __restrict__ src,
        const float* __restrict__ pos, const float* __restrict__ x,
        const int* __restrict__ rowptr, const int* __restrict__ elist,
        float inv2r, int n0, int Cin, int KdP, unsigned short* __restrict__ A){
    const int CH = 32, BK = 64;
    __shared__ float row[K3*32];
    __shared__ float xbuf[CH*32];
    __shared__ float ew[CH][8];
    __shared__ unsigned short bkt[8][BK];
    __shared__ int bcnt[8];
    __shared__ int esrc[CH];
    int tid = threadIdx.x;
    int node = n0 + blockIdx.x;
    int ci0 = blockIdx.y*32;
    for(int i=tid; i<K3*32; i+=256) row[i] = 0.f;
    int e0 = rowptr[node], e1 = rowptr[node+1];
    float pdx = pos[node*3+0], pdy = pos[node*3+1], pdz = pos[node*3+2];

    for(int c0=e0; c0<e1; c0+=CH){
        int cnt = min(CH, e1-c0);
        __syncthreads();
        if(tid < 8) bcnt[tid] = 0;
        float w[8]; int ki[8];
        if(tid < cnt){
            int e = elist[c0+tid];
            int s = src[e];
            esrc[tid] = s;
            spline_meta(pdx-pos[s*3+0], pdy-pos[s*3+1], pdz-pos[s*3+2], inv2r, w, ki);
            #pragma unroll
            for(int b=0;b<8;b++) ew[tid][b] = w[b];
        }
        __syncthreads();
        if(tid < cnt){
            #pragma unroll
            for(int b=0;b<8;b++){
                int g = ki[b] & 7;
                int p = atomicAdd(&bcnt[g], 1);
                bkt[g][p] = (unsigned short)((ki[b]<<8) | (tid<<3) | b);
            }
        }
        for(int i=tid; i<cnt*32; i+=256){
            int e = i >> 5, ci = i & 31;
            xbuf[i] = x[(size_t)esrc[e]*Cin + ci0 + ci];
        }
        __syncthreads();
        int g  = tid >> 5;
        int cl = tid & 31;
        int ng = bcnt[g];
        for(int i=0; i<ng; i++){
            unsigned v = bkt[g][i];
            int kq = v >> 8;
            int e  = (v >> 3) & 31;
            float wv = ew[e][v & 7];
            row[kq*32 + cl] += wv * xbuf[e*32 + cl];
        }
    }
    __syncthreads();
    size_t gbase = (size_t)blockIdx.x*KdP + ci0;
    for(int i=tid*4; i<K3*32; i+=1024){
        int k = i >> 5, c = i & 31;
        uint2 pk;
        pk.x = pk_bf16(row[i],   row[i+1]);
        pk.y = pk_bf16(row[i+2], row[i+3]);
        *(uint2*)&A[gbase + (size_t)k*Cin + c] = pk;
    }
}

// ---------------- build for Cin==1 (layer 1) ----------------
__global__ __launch_bounds__(256) void k_build1(const int* __restrict__ src,
        const float* __restrict__ pos, const float* __restrict__ x,
        const int* __restrict__ rowptr, const int* __restrict__ elist,
        float inv2r, int n0, int KdP, unsigned short* __restrict__ A){
    const int NB = 32, KD = K3;
    __shared__ float rows[NB*KD];
    int tid = threadIdx.x;
    for(int i=tid; i<NB*KD; i+=256) rows[i] = 0.f;
    __syncthreads();
    int nb = tid >> 3;
    int grp = tid & 7;
    int node = n0 + blockIdx.x*NB + nb;
    float* row = rows + nb*KD;
    float pdx = pos[node*3+0], pdy = pos[node*3+1], pdz = pos[node*3+2];
    int e0 = rowptr[node], e1 = rowptr[node+1];
    for(int ii=e0+grp; ii<e1; ii+=8){
        int e = elist[ii];
        int s = src[e];
        float w[8]; int ki[8];
        spline_meta(pdx-pos[s*3+0], pdy-pos[s*3+1], pdz-pos[s*3+2], inv2r, w, ki);
        float xs = x[s];
        #pragma unroll
        for(int b=0; b<8; b++)
            __hip_atomic_fetch_add(&row[ki[b]], w[b]*xs, __ATOMIC_RELAXED, __HIP_MEMORY_SCOPE_WORKGROUP);
    }
    __syncthreads();
    size_t gbase = (size_t)blockIdx.x*NB*KdP;
    int tot = NB*KdP;
    for(int i=tid*2; i<tot; i+=512){
        int nbw = i / KdP;
        int kk  = i - nbw*KdP;
        float v0 = (kk   < KD) ? rows[nbw*KD + kk]   : 0.f;
        float v1 = (kk+1 < KD) ? rows[nbw*KD + kk+1] : 0.f;
        *(unsigned*)&A[gbase + i] = pk_bf16(v0, v1);
    }
}

// ---------------- MFMA GEMM (BN in {32,64}) ----------------
template<int BN>
__global__ __launch_bounds__(256) void k_mfma(const unsigned short* __restrict__ A,
        const unsigned short* __restrict__ Wt, float* __restrict__ acc,
        int n0, int Co, int KdP, int Kper){
    const int NBF = BN/16;
    __shared__ unsigned short Al[128*32];
    __shared__ unsigned short Bl[BN*32];
    int tid = threadIdx.x;
    int m0 = blockIdx.x*128, nb0 = blockIdx.y*BN;
    int kstart = blockIdx.z*Kper;
    int kend = min(KdP, kstart + Kper);
    if(kstart >= kend) return;
    int w = tid >> 6, l = tid & 63, lm = l & 15, lk = l >> 4;
    f32x4 c[2][NBF];
    #pragma unroll
    for(int i=0;i<2;i++)
        #pragma unroll
        for(int j=0;j<NBF;j++) c[i][j] = (f32x4){0,0,0,0};
    int ar = tid >> 1, ah = (tid & 1)*16;

    for(int k0=kstart; k0<kend; k0+=32){
        const unsigned short* ga = A + (size_t)(m0+ar)*KdP + k0 + ah;
        *(uint4*)&Al[ar*32 + ah]     = *(const uint4*)ga;
        *(uint4*)&Al[ar*32 + ah + 8] = *(const uint4*)(ga + 8);
        if(tid < BN*4){
            int bn = tid >> 2, bk = (tid & 3)*8;
            *(uint4*)&Bl[bn*32 + bk] = *(const uint4*)(Wt + (size_t)(nb0+bn)*KdP + k0 + bk);
        }
        __syncthreads();
        bf16x8 af[2], bfr[NBF];
        #pragma unroll
        for(int i=0;i<2;i++) af[i] = *(bf16x8*)&Al[(w*32 + i*16 + lm)*32 + lk*8];
        #pragma unroll
        for(int j=0;j<NBF;j++) bfr[j] = *(bf16x8*)&Bl[(j*16 + lm)*32 + lk*8];
        #pragma unroll
        for(int i=0;i<2;i++)
            #pragma unroll
            for(int j=0;j<NBF;j++)
                c[i][j] = __builtin_amdgcn_mfma_f32_16x16x32_bf16(af[i], bfr[j], c[i][j], 0,0,0);
        __syncthreads();
    }
    #pragma unroll
    for(int i=0;i<2;i++){
        int mb = n0 + m0 + w*32 + i*16 + lk*4;
        #pragma unroll
        for(int j=0;j<NBF;j++){
            int col = nb0 + j*16 + lm;
            if(gridDim.z == 1){
                #pragma unroll
                for(int r=0;r<4;r++) acc[(size_t)(mb+r)*Co + col] = c[i][j][r];
            } else {
                #pragma unroll
                for(int r=0;r<4;r++) atomicAdd(&acc[(size_t)(mb+r)*Co + col], c[i][j][r]);
            }
        }
    }
}

// ---------------- conv epilogue + fused attention-pool atomics ----------------
__global__ void k_finish2(const float* __restrict__ acc, const int* __restrict__ deg,
        const float* __restrict__ xin, const float* __restrict__ root,
        const float* __restrict__ bias, const float* __restrict__ Wa,
        const float* __restrict__ ba, float* __restrict__ y,
        const int* __restrict__ cl, const float* __restrict__ pin,
        unsigned long long* __restrict__ m_p, float* __restrict__ cntf,
        float* __restrict__ ppos, int N, int Cin, int Co, int NPB){
    extern __shared__ float sm[];
    float* xs  = sm;
    float* red = sm + NPB*Cin;
    int tid = threadIdx.x;
    int nl = tid / Co, co = tid - nl*Co;
    int n = blockIdx.x*NPB + nl;
    bool act = (n < N);
    if(act) for(int c=co; c<Cin; c+=Co) xs[nl*Cin + c] = xin[(size_t)n*Cin + c];
    __syncthreads();
    float yv = 0.f;
    if(act){
        float v = acc[(size_t)n*Co + co] / (float)max(deg[n], 1);
        float rt = 0.f;
        for(int c=0; c<Cin; c++) rt += xs[nl*Cin + c]*root[(size_t)c*Co + co];
        v += rt + bias[co];
        yv = v > 0.f ? v : expm1f(v);
        y[(size_t)n*Co + co] = yv;
    }
    if(m_p){
        float av = act ? yv * Wa[co*2] : 0.f;
        if(Co <= 64){
            #pragma unroll
            for(int off=32; off>0; off>>=1)
                if(off < Co) av += __shfl_xor(av, off, 64);
        } else {
            red[tid] = av;
            __syncthreads();
            int cur = Co;
            while(cur > 1){
                int half = (cur+1) >> 1;
                if(co < cur-half) red[nl*Co+co] += red[nl*Co+co+half];
                __syncthreads();
                cur = half;
            }
            av = red[nl*Co];
        }
        if(act && co==0){
            float attv = av + ba[0];
            int c = cl[n];
            unsigned long long pk = ((unsigned long long)f2ord(attv) << 32) | (unsigned)(~n);
            atomicMax(&m_p[c], pk);
            atomicAdd(&cntf[c], 1.f);
            atomicAdd(&ppos[c*3+0], pin[n*3+0]);
            atomicAdd(&ppos[c*3+1], pin[n*3+1]);
            atomicAdd(&ppos[c*3+2], pin[n*3+2]);
        }
    }
}

// ---------------- pool gather ----------------
__global__ void k_pool3(const unsigned long long* __restrict__ m_p, const float* __restrict__ cntf,
        const float* __restrict__ ppos, const float* __restrict__ x,
        float* __restrict__ xo, float* __restrict__ poso, int nc, int Co, int nmax){
    int t = blockIdx.x*blockDim.x + threadIdx.x;
    if(t >= nc*Co) return;
    int c = t / Co;
    int co = t - c*Co;
    unsigned s = ~(unsigned)(m_p[c] & 0xFFFFFFFFull);
    s = min(s, (unsigned)(nmax-1));
    xo[(size_t)c*Co + co] = x[(size_t)s*Co + co];
    if(co < 3) poso[c*3+co] = ppos[c*3+co] / fmaxf(cntf[c], 1.f);
}

// ---------------- final voxel max pool ----------------
__global__ void k_vox(const float* __restrict__ x, const float* __restrict__ pos,
        unsigned* __restrict__ mx_u, float* __restrict__ cnt8){
    int nidx = blockIdx.x, ch = threadIdx.x;
    int v0 = min(max((int)floorf(pos[nidx*3+0]+0.5f),0),1);
    int v1 = min(max((int)floorf(pos[nidx*3+1]+0.5f),0),1);
    int v2 = min(max((int)floorf(pos[nidx*3+2]+0.5f),0),1);
    int b = nidx >> 3;
    int cl = b*8 + v0*4 + v1*2 + v2;
    atomicMax(&mx_u[cl*256+ch], f2ord(x[nidx*256+ch]));
    if(ch==0) atomicAdd(&cnt8[cl], 1.f);
}

// ---------------- FC + log_softmax ----------------
__global__ __launch_bounds__(256) void k_fc(const unsigned* __restrict__ mx_u,
        const float* __restrict__ cnt8, const float* __restrict__ Wfc,
        const float* __restrict__ bfc, float* __restrict__ out){
    __shared__ float sred[10][256];
    int b = blockIdx.x, tid = threadIdx.x;
    float p[10];
    #pragma unroll
    for(int j=0;j<10;j++) p[j]=0.f;
    for(int idx=tid; idx<2048; idx+=256){
        int v = idx >> 8;
        float val = (cnt8[b*8+v] > 0.f) ? ord2f(mx_u[b*2048+idx]) : 0.f;
        const float* wr = &Wfc[idx*10];
        #pragma unroll
        for(int j=0;j<10;j++) p[j] += val*wr[j];
    }
    #pragma unroll
    for(int j=0;j<10;j++) sred[j][tid]=p[j];
    __syncthreads();
    for(int s=128;s>0;s>>=1){
        if(tid<s){
            #pragma unroll
            for(int j=0;j<10;j++) sred[j][tid]+=sred[j][tid+s];
        }
        __syncthreads();
    }
    if(tid==0){
        float lg[10], mx=-1e30f, se=0.f;
        for(int j=0;j<10;j++){ lg[j]=sred[j][0]+bfc[j]; mx=fmaxf(mx,lg[j]); }
        for(int j=0;j<10;j++) se += expf(lg[j]-mx);
        float lse = mx + logf(se);
        for(int j=0;j<10;j++) out[b*10+j] = lg[j]-lse;
    }
}

extern "C" void kernel_launch(void* const* d_in, const int* in_sizes, int n_in,
                              void* d_out, int out_size, void* d_ws, size_t ws_size,
                              hipStream_t stream){
    const float* x0   = (const float*)d_in[0];
    const float* pos0 = (const float*)d_in[1];
    const float *Wc[5], *rootc[5], *bc[5];
    for(int i=0;i<5;i++){
        Wc[i]    = (const float*)d_in[2+3*i];
        rootc[i] = (const float*)d_in[3+3*i];
        bc[i]    = (const float*)d_in[4+3*i];
    }
    const float *Wa[4], *ba[4];
    for(int i=0;i<4;i++){
        Wa[i] = (const float*)d_in[17+2*i];
        ba[i] = (const float*)d_in[18+2*i];
    }
    const float* Wfc = (const float*)d_in[25];
    const float* bfc = (const float*)d_in[26];
    const int* ei[5]; for(int i=0;i<5;i++) ei[i] = (const int*)d_in[27+i];
    const int* cl[4]; for(int i=0;i<4;i++) cl[i] = (const int*)d_in[32+i];

    const int NPG[5]   = {2048,512,128,32,8};
    const int chans[6] = {1,32,64,96,128,256};
    const float inv2r[5] = {5.f,5.f,4.f,2.f,1.f};
    const int B = 32;
    int Ns[5], Es[5], KdPs[5];
    int totN=0, totE=0, totWt=0, accTot=0, poolTot=0;
    int nodeBase[5], edgeBase[5], wtBase[5], accOff[5], poolOff[4];
    for(int l=0;l<5;l++){
        Ns[l] = B*NPG[l]; Es[l] = Ns[l]*16;
        int Kd = K3*chans[l];
        KdPs[l] = (Kd + 31) & ~31;
        nodeBase[l] = totN; totN += Ns[l];
        edgeBase[l] = totE; totE += Es[l];
        wtBase[l] = totWt; totWt += chans[l+1]*KdPs[l];
        accOff[l] = accTot; accTot += Ns[l]*chans[l+1];
    }
    for(int l=0;l<4;l++){ poolOff[l] = poolTot; poolTot += Ns[l+1]; }

    size_t off = 0;
    auto alloc = [&](size_t bytes)->void*{
        void* p = (char*)d_ws + off;
        off = (off + bytes + 255) & ~(size_t)255;
        return p;
    };
    // ---- non-zeroed region ----
    float*    x_a    = (float*)   alloc((size_t)65536*32*4);
    float*    x_b    = (float*)   alloc((size_t)16384*32*4);
    float*    pos_a  = (float*)   alloc((size_t)16384*3*4);
    float*    pos_b  = (float*)   alloc((size_t)4096*3*4);
    int*      rowp_a = (int*)     alloc((size_t)(totN+5)*4);
    int*      curs_a = (int*)     alloc((size_t)totN*4);
    int*      elist_a= (int*)     alloc((size_t)totE*4);
    int*      bsum   = (int*)     alloc((size_t)32*4);
    unsigned short* Wt_a = (unsigned short*)alloc((size_t)totWt*2);
    // ---- zero region (single memset) ----
    size_t zstart = off;
    int*      deg_a  = (int*)     alloc((size_t)totN*4);
    float*    acc_a  = (float*)   alloc((size_t)accTot*4);
    unsigned long long* m_p_a = (unsigned long long*)alloc((size_t)poolTot*8);
    float*    cntf_a = (float*)   alloc((size_t)poolTot*4);
    float*    ppos_a = (float*)   alloc((size_t)poolTot*12);
    unsigned* mx_u   = (unsigned*)alloc((size_t)256*256*4);
    float*    cnt8   = (float*)   alloc((size_t)256*4);
    size_t zlen = off - zstart;
    // ---- A tail ----
    unsigned short* A = (unsigned short*)((char*)d_ws + off);
    size_t Abudget = (ws_size > off) ? (ws_size - off) : 0;

    CsrArgs ca; WtArgs wa;
    for(int l=0;l<5;l++){
        ca.dst[l] = ei[l] + Es[l];
        ca.deg[l] = deg_a + nodeBase[l];
        ca.elist[l] = elist_a + edgeBase[l];
        ca.E[l] = Es[l]; ca.N[l] = Ns[l];
        wa.W[l] = Wc[l]; wa.Wt[l] = Wt_a + wtBase[l];
        wa.Kd[l] = K3*chans[l]; wa.KdP[l] = KdPs[l]; wa.Co[l] = chans[l+1];
    }

    ScanTbl st;
    int nblk = 0;
    for(int l=0;l<5;l++){
        st.lfirst[l] = nblk;
        for(int ls=0; ls<Ns[l]; ls+=4096){
            st.degOff[nblk] = nodeBase[l] + ls;
            st.rpOff[nblk]  = nodeBase[l] + l + ls;
            st.curOff[nblk] = nodeBase[l] + ls;
            st.cnt[nblk]    = (Ns[l]-ls < 4096) ? (Ns[l]-ls) : 4096;
            nblk++;
        }
        st.rpNOff[l] = nodeBase[l] + l + Ns[l];
        st.Eval[l]   = Es[l];
    }
    st.lfirst[5] = nblk;

    hipMemsetAsync((char*)d_ws + zstart, 0, zlen, stream);
    k_pre<<<25480, 256, 0, stream>>>(ca, wa);
    k_scanA<<<nblk, 256, 0, stream>>>(st, deg_a, rowp_a, bsum);
    k_scanC<<<nblk, 256, 0, stream>>>(st, rowp_a, bsum, curs_a);
    k_fill_all2<<<dim3(4096,5), 256, 0, stream>>>(ca, curs_a+nodeBase[0], curs_a+nodeBase[1],
        curs_a+nodeBase[2], curs_a+nodeBase[3], curs_a+nodeBase[4]);

    const float* xin = x0;
    const float* pin = pos0;

    for(int L=0; L<5; L++){
        int N  = Ns[L];
        int Cin = chans[L], Co = chans[L+1];
        int KdP = KdPs[L];
        const int* srcp = ei[L];
        const int* rowptrL = rowp_a + nodeBase[L] + L;
        const int* elistL  = ca.elist[L];
        const unsigned short* WtL = wa.Wt[L];
        const int* degL = ca.deg[L];
        float* accL = acc_a + accOff[L];

        size_t nodeb = (size_t)KdP*2;
        int Mc = (int)(Abudget / nodeb);
        Mc = (Mc / 128) * 128;
        if(Mc < 128) Mc = 128;
        if(Mc > N) Mc = N;

        for(int rn0=0; rn0<N; rn0+=Mc){
            int rn1 = (rn0+Mc < N) ? rn0+Mc : N;
            int Mr  = rn1 - rn0;
            if(Cin==1)
                k_build1<<<Mr/32, 256, 0, stream>>>(srcp, pin, xin, rowptrL, elistL, inv2r[L], rn0, KdP, A);
            else
                k_build2<<<dim3(Mr, Cin/32), 256, 0, stream>>>(srcp, pin, xin, rowptrL, elistL,
                                                               inv2r[L], rn0, Cin, KdP, A);

            int BN = (Co % 64 == 0) ? 64 : 32;
            int gx = Mr/128, gy = Co/BN;
            int S = 768/(gx*gy);
            if(S < 1) S = 1;
            int maxS = KdP/32;
            if(S > maxS) S = maxS;
            int Kper = ((KdP + S - 1)/S + 31) & ~31;
            S = (KdP + Kper - 1)/Kper;
            dim3 g(gx, gy, S);
            if(BN == 64) k_mfma<64><<<g, 256, 0, stream>>>(A, WtL, accL, rn0, Co, KdP, Kper);
            else         k_mfma<32><<<g, 256, 0, stream>>>(A, WtL, accL, rn0, Co, KdP, Kper);
        }

        float* y = x_a;
        int NPB = 256/Co; if(NPB < 1) NPB = 1;
        int thr = NPB*Co;
        size_t smb = (size_t)(NPB*Cin + NPB*Co)*4;
        bool haspool = (L < 4);
        k_finish2<<<(N+NPB-1)/NPB, thr, smb, stream>>>(accL, degL, xin, rootc[L], bc[L],
            haspool?Wa[L]:nullptr, haspool?ba[L]:nullptr, y,
            haspool?cl[L]:nullptr, pin,
            haspool?(m_p_a+poolOff[L]):nullptr,
            haspool?(cntf_a+poolOff[L]):nullptr,
            haspool?(ppos_a+(size_t)poolOff[L]*3):nullptr,
            N, Cin, Co, NPB);

        if(haspool){
            int nc = Ns[L+1];
            float* pout = (L%2==0) ? pos_a : pos_b;
            k_pool3<<<(nc*Co+255)/256, 256, 0, stream>>>(m_p_a+poolOff[L], cntf_a+poolOff[L],
                ppos_a+(size_t)poolOff[L]*3, y, x_b, pout, nc, Co, N);
            xin = x_b; pin = pout;
        }
    }

    k_vox<<<256, 256, 0, stream>>>(x_a, pin, mx_u, cnt8);
    k_fc<<<32, 256, 0, stream>>>(mx_u, cnt8, Wfc, bfc, (float*)d_out);
}

// Round 12
// 535.834 us; speedup vs baseline: 1.0617x; 1.0171x over previous
//
#include <hip/hip_runtime.h>
#include <hip/hip_bf16.h>
#include <cstdint>
#include <cstddef>

#define KS 5
#define K3 125

typedef __attribute__((ext_vector_type(8))) short bf16x8;
typedef __attribute__((ext_vector_type(4))) float f32x4;

struct CsrArgs {
    const int* dst[5];
    int* deg[5];
    int* elist[5];
    int E[5];
    int N[5];
};
struct WtArgs {
    const float* W[5];
    unsigned short* Wt[5];
    int Kd[5], KdP[5], Co[5];
};
struct ScanTbl {
    int degOff[24]; int rpOff[24]; int curOff[24]; int cnt[24];
    int lfirst[6];
    int rpNOff[5]; int Eval[5];
};

__device__ __forceinline__ unsigned f2ord(float f){
    unsigned u = __float_as_uint(f);
    return (u & 0x80000000u) ? ~u : (u | 0x80000000u);
}
__device__ __forceinline__ float ord2f(unsigned u){
    unsigned b = (u & 0x80000000u) ? (u & 0x7FFFFFFFu) : ~u;
    return __uint_as_float(b);
}
__device__ __forceinline__ unsigned short f2bf(float f){
    unsigned u = __float_as_uint(f);
    u = (u + 0x7FFFu + ((u >> 16) & 1u)) >> 16;
    return (unsigned short)u;
}
__device__ __forceinline__ unsigned pk_bf16(float a, float b){
    __hip_bfloat162 p = __float22bfloat162_rn(make_float2(a, b));
    return *(unsigned*)&p;
}

// ---------------- fused preamble: degree histogram + W transpose/convert ----------------
__global__ __launch_bounds__(256) void k_pre(CsrArgs ca, WtArgs wa){
    __shared__ float t[64][65];
    int b = blockIdx.x;
    int tid = threadIdx.x;
    if(b < 20480){
        int l = b >> 12;
        int bx = b & 4095;
        int e = bx*256 + tid;
        if(e < ca.E[l]) atomicAdd(&ca.deg[l][ca.dst[l][e]], 1);
        return;
    }
    int r = b - 20480;
    int l = r / 1000;
    int rr = r - l*1000;
    int kb = (rr % 250)*64;
    int cb = (rr / 250)*64;
    int Kd = wa.Kd[l], KdP = wa.KdP[l], Co = wa.Co[l];
    if(kb >= KdP || cb >= Co) return;
    const float* W = wa.W[l];
    unsigned short* Wt = wa.Wt[l];
    int cc = tid & 63, rg = tid >> 6;
    #pragma unroll
    for(int i=0;i<16;i++){
        int kl = rg + i*4;
        int kk = kb + kl, co = cb + cc;
        t[kl][cc] = (kk < Kd && co < Co) ? W[(size_t)kk*Co + co] : 0.f;
    }
    __syncthreads();
    int kl = tid & 63;
    #pragma unroll
    for(int i=0;i<16;i++){
        int col = rg + i*4;
        int co = cb + col;
        int kk = kb + kl;
        if(co < Co && kk < KdP) Wt[(size_t)co*KdP + kk] = f2bf(t[kl][col]);
    }
}

// ---------------- hierarchical scan ----------------
__global__ __launch_bounds__(256) void k_scanA(ScanTbl t, const int* __restrict__ deg_a,
        int* __restrict__ rowp_a, int* __restrict__ bsum){
    __shared__ int part[256];
    int b = blockIdx.x;
    int n = t.cnt[b];
    const int* d = deg_a + t.degOff[b];
    int* rp = rowp_a + t.rpOff[b];
    int tid = threadIdx.x;
    int v[16]; int s = 0;
    #pragma unroll
    for(int j=0;j<16;j++){
        int idx = tid*16 + j;
        v[j] = (idx < n) ? d[idx] : 0;
        s += v[j];
    }
    part[tid] = s;
    __syncthreads();
    #pragma unroll
    for(int off=1; off<256; off<<=1){
        int val = (tid >= off) ? part[tid-off] : 0;
        __syncthreads();
        part[tid] += val;
        __syncthreads();
    }
    int run = tid ? part[tid-1] : 0;
    #pragma unroll
    for(int j=0;j<16;j++){
        int idx = tid*16 + j;
        if(idx < n){ rp[idx] = run; run += v[j]; }
    }
    if(tid == 255) bsum[b] = part[255];
}
__global__ __launch_bounds__(256) void k_scanC(ScanTbl t, int* __restrict__ rowp_a,
        const int* __restrict__ bsum, int* __restrict__ curs_a){
    __shared__ int soff;
    int b = blockIdx.x;
    int tid = threadIdx.x;
    int l = 0;
    while(b >= t.lfirst[l+1]) l++;
    if(tid == 0){
        int o = 0;
        for(int i=t.lfirst[l]; i<b; i++) o += bsum[i];
        soff = o;
        if(b == t.lfirst[l]) rowp_a[t.rpNOff[l]] = t.Eval[l];
    }
    __syncthreads();
    int n = t.cnt[b];
    int off = soff;
    int* rp = rowp_a + t.rpOff[b];
    int* cu = curs_a + t.curOff[b];
    for(int idx=tid; idx<n; idx+=256){
        int val = rp[idx] + off;
        rp[idx] = val;
        cu[idx] = val;
    }
}

// ---------------- CSR fill (all layers) ----------------
__global__ void k_fill_all2(CsrArgs a, int* curs0, int* curs1, int* curs2, int* curs3, int* curs4){
    int l = blockIdx.y;
    int* curs = (l==0)?curs0:(l==1)?curs1:(l==2)?curs2:(l==3)?curs3:curs4;
    int e = blockIdx.x*blockDim.x + threadIdx.x;
    if(e < a.E[l]){
        int p = atomicAdd(&curs[a.dst[l][e]], 1);
        a.elist[l][p] = e;
    }
}

// ---------------- spline basis helper ----------------
__device__ __forceinline__ void spline_meta(float dx, float dy, float dz, float inv2r,
        float* wgt, int* ki){
    float fr[3]; int k0[3];
    float dd[3] = {dx, dy, dz};
    #pragma unroll
    for(int dim=0; dim<3; dim++){
        float p = dd[dim]*inv2r + 0.5f;
        p = fminf(fmaxf(p, 0.f), 1.f);
        float u = p*4.0f;
        float kf = fminf(floorf(u), 3.f);
        fr[dim] = u - kf; k0[dim] = (int)kf;
    }
    #pragma unroll
    for(int bits=0; bits<8; bits++){
        wgt[bits] = ((bits&1)? fr[0] : 1.f-fr[0])
                  * ((bits&2)? fr[1] : 1.f-fr[1])
                  * ((bits&4)? fr[2] : 1.f-fr[2]);
        ki[bits]  = (k0[0]+(bits&1)) + KS*(k0[1]+((bits>>1)&1)) + KS*KS*(k0[2]+((bits>>2)&1));
    }
}

// ---------------- build A, 32-ci-slice per block, 16-group float2 drain ----------------
// Corner offsets {0,1,5,6,25,26,30,31} are pairwise distinct mod 16 -> each edge
// contributes <=1 entry per mod-16 bucket -> bkt[16][CH] can never overflow.
__global__ __launch_bounds__(256) void k_build2(const int* __restrict__ src,
        const float* __restrict__ pos, const float* __restrict__ x,
        const int* __restrict__ rowptr, const int* __restrict__ elist,
        float inv2r, int n0, int Cin, int KdP, unsigned short* __restrict__ A){
    const int CH = 32;
    __shared__ float row[K3*32];
    __shared__ float xbuf[CH*32];
    __shared__ float ew[CH][8];
    __shared__ unsigned short bkt[16][CH];
    __shared__ int bcnt[16];
    __shared__ int esrc[CH];
    int tid = threadIdx.x;
    int node = n0 + blockIdx.x;
    int ci0 = blockIdx.y*32;
    for(int i=tid; i<K3*32; i+=256) row[i] = 0.f;
    int e0 = rowptr[node], e1 = rowptr[node+1];
    float pdx = pos[node*3+0], pdy = pos[node*3+1], pdz = pos[node*3+2];

    for(int c0=e0; c0<e1; c0+=CH){
        int cnt = min(CH, e1-c0);
        __syncthreads();
        if(tid < 16) bcnt[tid] = 0;
        float w[8]; int ki[8];
        if(tid < cnt){
            int e = elist[c0+tid];
            int s = src[e];
            esrc[tid] = s;
            spline_meta(pdx-pos[s*3+0], pdy-pos[s*3+1], pdz-pos[s*3+2], inv2r, w, ki);
            #pragma unroll
            for(int b=0;b<8;b++) ew[tid][b] = w[b];
        }
        __syncthreads();
        if(tid < cnt){
            #pragma unroll
            for(int b=0;b<8;b++){
                int g = ki[b] & 15;
                int p = atomicAdd(&bcnt[g], 1);
                bkt[g][p] = (unsigned short)((ki[b]<<8) | (tid<<3) | b);
            }
        }
        for(int i=tid; i<cnt*32; i+=256){
            int e = i >> 5, ci = i & 31;
            xbuf[i] = x[(size_t)esrc[e]*Cin + ci0 + ci];
        }
        __syncthreads();
        int g  = tid >> 4;
        int cl = (tid & 15)*2;
        int ng = bcnt[g];
        for(int i=0; i<ng; i++){
            unsigned v = bkt[g][i];
            int kq = v >> 8;
            int e  = (v >> 3) & 31;
            float wv = ew[e][v & 7];
            float2 xv = *(float2*)&xbuf[e*32 + cl];
            float2* rp = (float2*)&row[kq*32 + cl];
            float2 rv = *rp;
            rv.x += wv*xv.x;
            rv.y += wv*xv.y;
            *rp = rv;
        }
    }
    __syncthreads();
    size_t gbase = (size_t)blockIdx.x*KdP + ci0;
    for(int i=tid*4; i<K3*32; i+=1024){
        int k = i >> 5, c = i & 31;
        uint2 pk;
        pk.x = pk_bf16(row[i],   row[i+1]);
        pk.y = pk_bf16(row[i+2], row[i+3]);
        *(uint2*)&A[gbase + (size_t)k*Cin + c] = pk;
    }
}

// ---------------- build for Cin==1 (layer 1) ----------------
__global__ __launch_bounds__(256) void k_build1(const int* __restrict__ src,
        const float* __restrict__ pos, const float* __restrict__ x,
        const int* __restrict__ rowptr, const int* __restrict__ elist,
        float inv2r, int n0, int KdP, unsigned short* __restrict__ A){
    const int NB = 32, KD = K3;
    __shared__ float rows[NB*KD];
    int tid = threadIdx.x;
    for(int i=tid; i<NB*KD; i+=256) rows[i] = 0.f;
    __syncthreads();
    int nb = tid >> 3;
    int grp = tid & 7;
    int node = n0 + blockIdx.x*NB + nb;
    float* row = rows + nb*KD;
    float pdx = pos[node*3+0], pdy = pos[node*3+1], pdz = pos[node*3+2];
    int e0 = rowptr[node], e1 = rowptr[node+1];
    for(int ii=e0+grp; ii<e1; ii+=8){
        int e = elist[ii];
        int s = src[e];
        float w[8]; int ki[8];
        spline_meta(pdx-pos[s*3+0], pdy-pos[s*3+1], pdz-pos[s*3+2], inv2r, w, ki);
        float xs = x[s];
        #pragma unroll
        for(int b=0; b<8; b++)
            __hip_atomic_fetch_add(&row[ki[b]], w[b]*xs, __ATOMIC_RELAXED, __HIP_MEMORY_SCOPE_WORKGROUP);
    }
    __syncthreads();
    size_t gbase = (size_t)blockIdx.x*NB*KdP;
    int tot = NB*KdP;
    for(int i=tid*2; i<tot; i+=512){
        int nbw = i / KdP;
        int kk  = i - nbw*KdP;
        float v0 = (kk   < KD) ? rows[nbw*KD + kk]   : 0.f;
        float v1 = (kk+1 < KD) ? rows[nbw*KD + kk+1] : 0.f;
        *(unsigned*)&A[gbase + i] = pk_bf16(v0, v1);
    }
}

// ---------------- MFMA GEMM (BN in {32,64}) ----------------
template<int BN>
__global__ __launch_bounds__(256) void k_mfma(const unsigned short* __restrict__ A,
        const unsigned short* __restrict__ Wt, float* __restrict__ acc,
        int n0, int Co, int KdP, int Kper){
    const int NBF = BN/16;
    __shared__ unsigned short Al[128*32];
    __shared__ unsigned short Bl[BN*32];
    int tid = threadIdx.x;
    int m0 = blockIdx.x*128, nb0 = blockIdx.y*BN;
    int kstart = blockIdx.z*Kper;
    int kend = min(KdP, kstart + Kper);
    if(kstart >= kend) return;
    int w = tid >> 6, l = tid & 63, lm = l & 15, lk = l >> 4;
    f32x4 c[2][NBF];
    #pragma unroll
    for(int i=0;i<2;i++)
        #pragma unroll
        for(int j=0;j<NBF;j++) c[i][j] = (f32x4){0,0,0,0};
    int ar = tid >> 1, ah = (tid & 1)*16;

    for(int k0=kstart; k0<kend; k0+=32){
        const unsigned short* ga = A + (size_t)(m0+ar)*KdP + k0 + ah;
        *(uint4*)&Al[ar*32 + ah]     = *(const uint4*)ga;
        *(uint4*)&Al[ar*32 + ah + 8] = *(const uint4*)(ga + 8);
        if(tid < BN*4){
            int bn = tid >> 2, bk = (tid & 3)*8;
            *(uint4*)&Bl[bn*32 + bk] = *(const uint4*)(Wt + (size_t)(nb0+bn)*KdP + k0 + bk);
        }
        __syncthreads();
        bf16x8 af[2], bfr[NBF];
        #pragma unroll
        for(int i=0;i<2;i++) af[i] = *(bf16x8*)&Al[(w*32 + i*16 + lm)*32 + lk*8];
        #pragma unroll
        for(int j=0;j<NBF;j++) bfr[j] = *(bf16x8*)&Bl[(j*16 + lm)*32 + lk*8];
        #pragma unroll
        for(int i=0;i<2;i++)
            #pragma unroll
            for(int j=0;j<NBF;j++)
                c[i][j] = __builtin_amdgcn_mfma_f32_16x16x32_bf16(af[i], bfr[j], c[i][j], 0,0,0);
        __syncthreads();
    }
    #pragma unroll
    for(int i=0;i<2;i++){
        int mb = n0 + m0 + w*32 + i*16 + lk*4;
        #pragma unroll
        for(int j=0;j<NBF;j++){
            int col = nb0 + j*16 + lm;
            if(gridDim.z == 1){
                #pragma unroll
                for(int r=0;r<4;r++) acc[(size_t)(mb+r)*Co + col] = c[i][j][r];
            } else {
                #pragma unroll
                for(int r=0;r<4;r++) atomicAdd(&acc[(size_t)(mb+r)*Co + col], c[i][j][r]);
            }
        }
    }
}

// ---------------- conv epilogue + fused attention-pool atomics ----------------
__global__ void k_finish2(const float* __restrict__ acc, const int* __restrict__ deg,
        const float* __restrict__ xin, const float* __restrict__ root,
        const float* __restrict__ bias, const float* __restrict__ Wa,
        const float* __restrict__ ba, float* __restrict__ y,
        const int* __restrict__ cl, const float* __restrict__ pin,
        unsigned long long* __restrict__ m_p, float* __restrict__ cntf,
        float* __restrict__ ppos, int N, int Cin, int Co, int NPB){
    extern __shared__ float sm[];
    float* xs  = sm;
    float* red = sm + NPB*Cin;
    int tid = threadIdx.x;
    int nl = tid / Co, co = tid - nl*Co;
    int n = blockIdx.x*NPB + nl;
    bool act = (n < N);
    if(act) for(int c=co; c<Cin; c+=Co) xs[nl*Cin + c] = xin[(size_t)n*Cin + c];
    __syncthreads();
    float yv = 0.f;
    if(act){
        float v = acc[(size_t)n*Co + co] / (float)max(deg[n], 1);
        float rt = 0.f;
        for(int c=0; c<Cin; c++) rt += xs[nl*Cin + c]*root[(size_t)c*Co + co];
        v += rt + bias[co];
        yv = v > 0.f ? v : expm1f(v);
        y[(size_t)n*Co + co] = yv;
    }
    if(m_p){
        float av = act ? yv * Wa[co*2] : 0.f;
        if(Co <= 64){
            #pragma unroll
            for(int off=32; off>0; off>>=1)
                if(off < Co) av += __shfl_xor(av, off, 64);
        } else {
            red[tid] = av;
            __syncthreads();
            int cur = Co;
            while(cur > 1){
                int half = (cur+1) >> 1;
                if(co < cur-half) red[nl*Co+co] += red[nl*Co+co+half];
                __syncthreads();
                cur = half;
            }
            av = red[nl*Co];
        }
        if(act && co==0){
            float attv = av + ba[0];
            int c = cl[n];
            unsigned long long pk = ((unsigned long long)f2ord(attv) << 32) | (unsigned)(~n);
            atomicMax(&m_p[c], pk);
            atomicAdd(&cntf[c], 1.f);
            atomicAdd(&ppos[c*3+0], pin[n*3+0]);
            atomicAdd(&ppos[c*3+1], pin[n*3+1]);
            atomicAdd(&ppos[c*3+2], pin[n*3+2]);
        }
    }
}

// ---------------- pool gather ----------------
__global__ void k_pool3(const unsigned long long* __restrict__ m_p, const float* __restrict__ cntf,
        const float* __restrict__ ppos, const float* __restrict__ x,
        float* __restrict__ xo, float* __restrict__ poso, int nc, int Co, int nmax){
    int t = blockIdx.x*blockDim.x + threadIdx.x;
    if(t >= nc*Co) return;
    int c = t / Co;
    int co = t - c*Co;
    unsigned s = ~(unsigned)(m_p[c] & 0xFFFFFFFFull);
    s = min(s, (unsigned)(nmax-1));
    xo[(size_t)c*Co + co] = x[(size_t)s*Co + co];
    if(co < 3) poso[c*3+co] = ppos[c*3+co] / fmaxf(cntf[c], 1.f);
}

// ---------------- final voxel max pool ----------------
__global__ void k_vox(const float* __restrict__ x, const float* __restrict__ pos,
        unsigned* __restrict__ mx_u, float* __restrict__ cnt8){
    int nidx = blockIdx.x, ch = threadIdx.x;
    int v0 = min(max((int)floorf(pos[nidx*3+0]+0.5f),0),1);
    int v1 = min(max((int)floorf(pos[nidx*3+1]+0.5f),0),1);
    int v2 = min(max((int)floorf(pos[nidx*3+2]+0.5f),0),1);
    int b = nidx >> 3;
    int cl = b*8 + v0*4 + v1*2 + v2;
    atomicMax(&mx_u[cl*256+ch], f2ord(x[nidx*256+ch]));
    if(ch==0) atomicAdd(&cnt8[cl], 1.f);
}

// ---------------- FC + log_softmax ----------------
__global__ __launch_bounds__(256) void k_fc(const unsigned* __restrict__ mx_u,
        const float* __restrict__ cnt8, const float* __restrict__ Wfc,
        const float* __restrict__ bfc, float* __restrict__ out){
    __shared__ float sred[10][256];
    int b = blockIdx.x, tid = threadIdx.x;
    float p[10];
    #pragma unroll
    for(int j=0;j<10;j++) p[j]=0.f;
    for(int idx=tid; idx<2048; idx+=256){
        int v = idx >> 8;
        float val = (cnt8[b*8+v] > 0.f) ? ord2f(mx_u[b*2048+idx]) : 0.f;
        const float* wr = &Wfc[idx*10];
        #pragma unroll
        for(int j=0;j<10;j++) p[j] += val*wr[j];
    }
    #pragma unroll
    for(int j=0;j<10;j++) sred[j][tid]=p[j];
    __syncthreads();
    for(int s=128;s>0;s>>=1){
        if(tid<s){
            #pragma unroll
            for(int j=0;j<10;j++) sred[j][tid]+=sred[j][tid+s];
        }
        __syncthreads();
    }
    if(tid==0){
        float lg[10], mx=-1e30f, se=0.f;
        for(int j=0;j<10;j++){ lg[j]=sred[j][0]+bfc[j]; mx=fmaxf(mx,lg[j]); }
        for(int j=0;j<10;j++) se += expf(lg[j]-mx);
        float lse = mx + logf(se);
        for(int j=0;j<10;j++) out[b*10+j] = lg[j]-lse;
    }
}

extern "C" void kernel_launch(void* const* d_in, const int* in_sizes, int n_in,
                              void* d_out, int out_size, void* d_ws, size_t ws_size,
                              hipStream_t stream){
    const float* x0   = (const float*)d_in[0];
    const float* pos0 = (const float*)d_in[1];
    const float *Wc[5], *rootc[5], *bc[5];
    for(int i=0;i<5;i++){
        Wc[i]    = (const float*)d_in[2+3*i];
        rootc[i] = (const float*)d_in[3+3*i];
        bc[i]    = (const float*)d_in[4+3*i];
    }
    const float *Wa[4], *ba[4];
    for(int i=0;i<4;i++){
        Wa[i] = (const float*)d_in[17+2*i];
        ba[i] = (const float*)d_in[18+2*i];
    }
    const float* Wfc = (const float*)d_in[25];
    const float* bfc = (const float*)d_in[26];
    const int* ei[5]; for(int i=0;i<5;i++) ei[i] = (const int*)d_in[27+i];
    const int* cl[4]; for(int i=0;i<4;i++) cl[i] = (const int*)d_in[32+i];

    const int NPG[5]   = {2048,512,128,32,8};
    const int chans[6] = {1,32,64,96,128,256};
    const float inv2r[5] = {5.f,5.f,4.f,2.f,1.f};
    const int B = 32;
    int Ns[5], Es[5], KdPs[5];
    int totN=0, totE=0, totWt=0, accTot=0, poolTot=0;
    int nodeBase[5], edgeBase[5], wtBase[5], accOff[5], poolOff[4];
    for(int l=0;l<5;l++){
        Ns[l] = B*NPG[l]; Es[l] = Ns[l]*16;
        int Kd = K3*chans[l];
        KdPs[l] = (Kd + 31) & ~31;
        nodeBase[l] = totN; totN += Ns[l];
        edgeBase[l] = totE; totE += Es[l];
        wtBase[l] = totWt; totWt += chans[l+1]*KdPs[l];
        accOff[l] = accTot; accTot += Ns[l]*chans[l+1];
    }
    for(int l=0;l<4;l++){ poolOff[l] = poolTot; poolTot += Ns[l+1]; }

    size_t off = 0;
    auto alloc = [&](size_t bytes)->void*{
        void* p = (char*)d_ws + off;
        off = (off + bytes + 255) & ~(size_t)255;
        return p;
    };
    // ---- non-zeroed region ----
    float*    x_a    = (float*)   alloc((size_t)65536*32*4);
    float*    x_b    = (float*)   alloc((size_t)16384*32*4);
    float*    pos_a  = (float*)   alloc((size_t)16384*3*4);
    float*    pos_b  = (float*)   alloc((size_t)4096*3*4);
    int*      rowp_a = (int*)     alloc((size_t)(totN+5)*4);
    int*      curs_a = (int*)     alloc((size_t)totN*4);
    int*      elist_a= (int*)     alloc((size_t)totE*4);
    int*      bsum   = (int*)     alloc((size_t)32*4);
    unsigned short* Wt_a = (unsigned short*)alloc((size_t)totWt*2);
    // ---- zero region (single memset) ----
    size_t zstart = off;
    int*      deg_a  = (int*)     alloc((size_t)totN*4);
    float*    acc_a  = (float*)   alloc((size_t)accTot*4);
    unsigned long long* m_p_a = (unsigned long long*)alloc((size_t)poolTot*8);
    float*    cntf_a = (float*)   alloc((size_t)poolTot*4);
    float*    ppos_a = (float*)   alloc((size_t)poolTot*12);
    unsigned* mx_u   = (unsigned*)alloc((size_t)256*256*4);
    float*    cnt8   = (float*)   alloc((size_t)256*4);
    size_t zlen = off - zstart;
    // ---- A tail ----
    unsigned short* A = (unsigned short*)((char*)d_ws + off);
    size_t Abudget = (ws_size > off) ? (ws_size - off) : 0;

    CsrArgs ca; WtArgs wa;
    for(int l=0;l<5;l++){
        ca.dst[l] = ei[l] + Es[l];
        ca.deg[l] = deg_a + nodeBase[l];
        ca.elist[l] = elist_a + edgeBase[l];
        ca.E[l] = Es[l]; ca.N[l] = Ns[l];
        wa.W[l] = Wc[l]; wa.Wt[l] = Wt_a + wtBase[l];
        wa.Kd[l] = K3*chans[l]; wa.KdP[l] = KdPs[l]; wa.Co[l] = chans[l+1];
    }

    ScanTbl st;
    int nblk = 0;
    for(int l=0;l<5;l++){
        st.lfirst[l] = nblk;
        for(int ls=0; ls<Ns[l]; ls+=4096){
            st.degOff[nblk] = nodeBase[l] + ls;
            st.rpOff[nblk]  = nodeBase[l] + l + ls;
            st.curOff[nblk] = nodeBase[l] + ls;
            st.cnt[nblk]    = (Ns[l]-ls < 4096) ? (Ns[l]-ls) : 4096;
            nblk++;
        }
        st.rpNOff[l] = nodeBase[l] + l + Ns[l];
        st.Eval[l]   = Es[l];
    }
    st.lfirst[5] = nblk;

    hipMemsetAsync((char*)d_ws + zstart, 0, zlen, stream);
    k_pre<<<25480, 256, 0, stream>>>(ca, wa);
    k_scanA<<<nblk, 256, 0, stream>>>(st, deg_a, rowp_a, bsum);
    k_scanC<<<nblk, 256, 0, stream>>>(st, rowp_a, bsum, curs_a);
    k_fill_all2<<<dim3(4096,5), 256, 0, stream>>>(ca, curs_a+nodeBase[0], curs_a+nodeBase[1],
        curs_a+nodeBase[2], curs_a+nodeBase[3], curs_a+nodeBase[4]);

    const float* xin = x0;
    const float* pin = pos0;

    for(int L=0; L<5; L++){
        int N  = Ns[L];
        int Cin = chans[L], Co = chans[L+1];
        int KdP = KdPs[L];
        const int* srcp = ei[L];
        const int* rowptrL = rowp_a + nodeBase[L] + L;
        const int* elistL  = ca.elist[L];
        const unsigned short* WtL = wa.Wt[L];
        const int* degL = ca.deg[L];
        float* accL = acc_a + accOff[L];

        size_t nodeb = (size_t)KdP*2;
        int Mc = (int)(Abudget / nodeb);
        Mc = (Mc / 128) * 128;
        if(Mc < 128) Mc = 128;
        if(Mc > N) Mc = N;

        for(int rn0=0; rn0<N; rn0+=Mc){
            int rn1 = (rn0+Mc < N) ? rn0+Mc : N;
            int Mr  = rn1 - rn0;
            if(Cin==1)
                k_build1<<<Mr/32, 256, 0, stream>>>(srcp, pin, xin, rowptrL, elistL, inv2r[L], rn0, KdP, A);
            else
                k_build2<<<dim3(Mr, Cin/32), 256, 0, stream>>>(srcp, pin, xin, rowptrL, elistL,
                                                               inv2r[L], rn0, Cin, KdP, A);

            int BN = (Co % 64 == 0) ? 64 : 32;
            int gx = Mr/128, gy = Co/BN;
            int S = 768/(gx*gy);
            if(S < 1) S = 1;
            int maxS = KdP/32;
            if(S > maxS) S = maxS;
            int Kper = ((KdP + S - 1)/S + 31) & ~31;
            S = (KdP + Kper - 1)/Kper;
            dim3 g(gx, gy, S);
            if(BN == 64) k_mfma<64><<<g, 256, 0, stream>>>(A, WtL, accL, rn0, Co, KdP, Kper);
            else         k_mfma<32><<<g, 256, 0, stream>>>(A, WtL, accL, rn0, Co, KdP, Kper);
        }

        float* y = x_a;
        int NPB = 256/Co; if(NPB < 1) NPB = 1;
        int thr = NPB*Co;
        size_t smb = (size_t)(NPB*Cin + NPB*Co)*4;
        bool haspool = (L < 4);
        k_finish2<<<(N+NPB-1)/NPB, thr, smb, stream>>>(accL, degL, xin, rootc[L], bc[L],
            haspool?Wa[L]:nullptr, haspool?ba[L]:nullptr, y,
            haspool?cl[L]:nullptr, pin,
            haspool?(m_p_a+poolOff[L]):nullptr,
            haspool?(cntf_a+poolOff[L]):nullptr,
            haspool?(ppos_a+(size_t)poolOff[L]*3):nullptr,
            N, Cin, Co, NPB);

        if(haspool){
            int nc = Ns[L+1];
            float* pout = (L%2==0) ? pos_a : pos_b;
            k_pool3<<<(nc*Co+255)/256, 256, 0, stream>>>(m_p_a+poolOff[L], cntf_a+poolOff[L],
                ppos_a+(size_t)poolOff[L]*3, y, x_b, pout, nc, Co, N);
            xin = x_b; pin = pout;
        }
    }

    k_vox<<<256, 256, 0, stream>>>(x_a, pin, mx_u, cnt8);
    k_fc<<<32, 256, 0, stream>>>(mx_u, cnt8, Wfc, bfc, (float*)d_out);
}

// Round 13
// 471.958 us; speedup vs baseline: 1.2054x; 1.1353x over previous
//
#include <hip/hip_runtime.h>
#include <hip/hip_bf16.h>
#include <cstdint>
#include <cstddef>

#define KS 5
#define K3 125

typedef __attribute__((ext_vector_type(8))) short bf16x8;
typedef __attribute__((ext_vector_type(4))) float f32x4;

struct PreArgs {
    const int* src[5]; const int* dst[5];
    int* cnt[5]; int* slots[5];
    int E[5];
    const float* W[5]; unsigned short* Wt[5];
    int Kd[5], KdP[5], Co[5];
    int fillFirst[6]; int wtFirst[6]; int ktiles[5];
};

__device__ __forceinline__ unsigned f2ord(float f){
    unsigned u = __float_as_uint(f);
    return (u & 0x80000000u) ? ~u : (u | 0x80000000u);
}
__device__ __forceinline__ float ord2f(unsigned u){
    unsigned b = (u & 0x80000000u) ? (u & 0x7FFFFFFFu) : ~u;
    return __uint_as_float(b);
}
__device__ __forceinline__ unsigned short f2bf(float f){
    unsigned u = __float_as_uint(f);
    u = (u + 0x7FFFu + ((u >> 16) & 1u)) >> 16;
    return (unsigned short)u;
}
__device__ __forceinline__ unsigned pk_bf16(float a, float b){
    __hip_bfloat162 p = __float22bfloat162_rn(make_float2(a, b));
    return *(unsigned*)&p;
}

// ---------------- fused preamble: capacity-slot fill + W transpose/convert ----------------
__global__ __launch_bounds__(256) void k_pre2(PreArgs a){
    __shared__ float t[64][65];
    int b = blockIdx.x;
    int tid = threadIdx.x;
    if(b < a.fillFirst[5]){
        int l = 0;
        while(b >= a.fillFirst[l+1]) l++;
        int e = (b - a.fillFirst[l])*256 + tid;
        if(e < a.E[l]){
            int d = a.dst[l][e];
            int s = a.src[l][e];
            int p = atomicAdd(&a.cnt[l][d], 1);
            if(p < 64) a.slots[l][(size_t)d*64 + p] = s;
        }
        return;
    }
    int r = b - a.fillFirst[5];
    int l = 0;
    while(r >= a.wtFirst[l+1]) l++;
    int idx = r - a.wtFirst[l];
    int kb = (idx % a.ktiles[l])*64;
    int cb = (idx / a.ktiles[l])*64;
    int Kd = a.Kd[l], KdP = a.KdP[l], Co = a.Co[l];
    const float* W = a.W[l];
    unsigned short* Wt = a.Wt[l];
    int cc = tid & 63, rg = tid >> 6;
    #pragma unroll
    for(int i=0;i<16;i++){
        int kl = rg + i*4;
        int kk = kb + kl, co = cb + cc;
        t[kl][cc] = (kk < Kd && co < Co) ? W[(size_t)kk*Co + co] : 0.f;
    }
    __syncthreads();
    int kl = tid & 63;
    #pragma unroll
    for(int i=0;i<16;i++){
        int col = rg + i*4;
        int co = cb + col;
        int kk = kb + kl;
        if(co < Co && kk < KdP) Wt[(size_t)co*KdP + kk] = f2bf(t[kl][col]);
    }
}

// ---------------- spline basis helper ----------------
__device__ __forceinline__ void spline_meta(float dx, float dy, float dz, float inv2r,
        float* wgt, int* ki){
    float fr[3]; int k0[3];
    float dd[3] = {dx, dy, dz};
    #pragma unroll
    for(int dim=0; dim<3; dim++){
        float p = dd[dim]*inv2r + 0.5f;
        p = fminf(fmaxf(p, 0.f), 1.f);
        float u = p*4.0f;
        float kf = fminf(floorf(u), 3.f);
        fr[dim] = u - kf; k0[dim] = (int)kf;
    }
    #pragma unroll
    for(int bits=0; bits<8; bits++){
        wgt[bits] = ((bits&1)? fr[0] : 1.f-fr[0])
                  * ((bits&2)? fr[1] : 1.f-fr[1])
                  * ((bits&4)? fr[2] : 1.f-fr[2]);
        ki[bits]  = (k0[0]+(bits&1)) + KS*(k0[1]+((bits>>1)&1)) + KS*KS*(k0[2]+((bits>>2)&1));
    }
}

// ---------------- build A, 32-ci-slice per block, 16-group float2 drain ----------------
__global__ __launch_bounds__(256) void k_build2(const int* __restrict__ slots,
        const int* __restrict__ cnt, const float* __restrict__ pos,
        const float* __restrict__ x,
        float inv2r, int n0, int Cin, int KdP, unsigned short* __restrict__ A){
    const int CH = 32;
    __shared__ float row[K3*32];
    __shared__ float xbuf[CH*32];
    __shared__ float ew[CH][8];
    __shared__ unsigned short bkt[16][CH];
    __shared__ int bcnt[16];
    __shared__ int esrc[CH];
    int tid = threadIdx.x;
    int node = n0 + blockIdx.x;
    int ci0 = blockIdx.y*32;
    for(int i=tid; i<K3*32; i+=256) row[i] = 0.f;
    int ecnt = min(cnt[node], 64);
    const int* sl = slots + (size_t)node*64;
    float pdx = pos[node*3+0], pdy = pos[node*3+1], pdz = pos[node*3+2];

    for(int c0=0; c0<ecnt; c0+=CH){
        int cc2 = min(CH, ecnt-c0);
        __syncthreads();
        if(tid < 16) bcnt[tid] = 0;
        float w[8]; int ki[8];
        if(tid < cc2){
            int s = sl[c0+tid];
            esrc[tid] = s;
            spline_meta(pdx-pos[s*3+0], pdy-pos[s*3+1], pdz-pos[s*3+2], inv2r, w, ki);
            #pragma unroll
            for(int b=0;b<8;b++) ew[tid][b] = w[b];
        }
        __syncthreads();
        if(tid < cc2){
            #pragma unroll
            for(int b=0;b<8;b++){
                int g = ki[b] & 15;
                int p = atomicAdd(&bcnt[g], 1);
                bkt[g][p] = (unsigned short)((ki[b]<<8) | (tid<<3) | b);
            }
        }
        for(int i=tid; i<cc2*32; i+=256){
            int e = i >> 5, ci = i & 31;
            xbuf[i] = x[(size_t)esrc[e]*Cin + ci0 + ci];
        }
        __syncthreads();
        int g  = tid >> 4;
        int cl = (tid & 15)*2;
        int ng = bcnt[g];
        for(int i=0; i<ng; i++){
            unsigned v = bkt[g][i];
            int kq = v >> 8;
            int e  = (v >> 3) & 31;
            float wv = ew[e][v & 7];
            float2 xv = *(float2*)&xbuf[e*32 + cl];
            float2* rp = (float2*)&row[kq*32 + cl];
            float2 rv = *rp;
            rv.x += wv*xv.x;
            rv.y += wv*xv.y;
            *rp = rv;
        }
    }
    __syncthreads();
    size_t gbase = (size_t)blockIdx.x*KdP + ci0;
    for(int i=tid*4; i<K3*32; i+=1024){
        int k = i >> 5, c = i & 31;
        uint2 pk;
        pk.x = pk_bf16(row[i],   row[i+1]);
        pk.y = pk_bf16(row[i+2], row[i+3]);
        *(uint2*)&A[gbase + (size_t)k*Cin + c] = pk;
    }
}

// ---------------- build for Cin==1 (layer 1) ----------------
__global__ __launch_bounds__(256) void k_build1(const int* __restrict__ slots,
        const int* __restrict__ cnt, const float* __restrict__ pos,
        const float* __restrict__ x,
        float inv2r, int n0, int KdP, unsigned short* __restrict__ A){
    const int NB = 32, KD = K3;
    __shared__ float rows[NB*KD];
    int tid = threadIdx.x;
    for(int i=tid; i<NB*KD; i+=256) rows[i] = 0.f;
    __syncthreads();
    int nb = tid >> 3;
    int grp = tid & 7;
    int node = n0 + blockIdx.x*NB + nb;
    float* row = rows + nb*KD;
    float pdx = pos[node*3+0], pdy = pos[node*3+1], pdz = pos[node*3+2];
    int ecnt = min(cnt[node], 64);
    const int* sl = slots + (size_t)node*64;
    for(int ii=grp; ii<ecnt; ii+=8){
        int s = sl[ii];
        float w[8]; int ki[8];
        spline_meta(pdx-pos[s*3+0], pdy-pos[s*3+1], pdz-pos[s*3+2], inv2r, w, ki);
        float xs = x[s];
        #pragma unroll
        for(int b=0; b<8; b++)
            __hip_atomic_fetch_add(&row[ki[b]], w[b]*xs, __ATOMIC_RELAXED, __HIP_MEMORY_SCOPE_WORKGROUP);
    }
    __syncthreads();
    size_t gbase = (size_t)blockIdx.x*NB*KdP;
    int tot = NB*KdP;
    for(int i=tid*2; i<tot; i+=512){
        int nbw = i / KdP;
        int kk  = i - nbw*KdP;
        float v0 = (kk   < KD) ? rows[nbw*KD + kk]   : 0.f;
        float v1 = (kk+1 < KD) ? rows[nbw*KD + kk+1] : 0.f;
        *(unsigned*)&A[gbase + i] = pk_bf16(v0, v1);
    }
}

// ---------------- MFMA GEMM (BN in {32,64}) ----------------
template<int BN>
__global__ __launch_bounds__(256) void k_mfma(const unsigned short* __restrict__ A,
        const unsigned short* __restrict__ Wt, float* __restrict__ acc,
        int n0, int Co, int KdP, int Kper){
    const int NBF = BN/16;
    __shared__ unsigned short Al[128*32];
    __shared__ unsigned short Bl[BN*32];
    int tid = threadIdx.x;
    int m0 = blockIdx.x*128, nb0 = blockIdx.y*BN;
    int kstart = blockIdx.z*Kper;
    int kend = min(KdP, kstart + Kper);
    if(kstart >= kend) return;
    int w = tid >> 6, l = tid & 63, lm = l & 15, lk = l >> 4;
    f32x4 c[2][NBF];
    #pragma unroll
    for(int i=0;i<2;i++)
        #pragma unroll
        for(int j=0;j<NBF;j++) c[i][j] = (f32x4){0,0,0,0};
    int ar = tid >> 1, ah = (tid & 1)*16;

    for(int k0=kstart; k0<kend; k0+=32){
        const unsigned short* ga = A + (size_t)(m0+ar)*KdP + k0 + ah;
        *(uint4*)&Al[ar*32 + ah]     = *(const uint4*)ga;
        *(uint4*)&Al[ar*32 + ah + 8] = *(const uint4*)(ga + 8);
        if(tid < BN*4){
            int bn = tid >> 2, bk = (tid & 3)*8;
            *(uint4*)&Bl[bn*32 + bk] = *(const uint4*)(Wt + (size_t)(nb0+bn)*KdP + k0 + bk);
        }
        __syncthreads();
        bf16x8 af[2], bfr[NBF];
        #pragma unroll
        for(int i=0;i<2;i++) af[i] = *(bf16x8*)&Al[(w*32 + i*16 + lm)*32 + lk*8];
        #pragma unroll
        for(int j=0;j<NBF;j++) bfr[j] = *(bf16x8*)&Bl[(j*16 + lm)*32 + lk*8];
        #pragma unroll
        for(int i=0;i<2;i++)
            #pragma unroll
            for(int j=0;j<NBF;j++)
                c[i][j] = __builtin_amdgcn_mfma_f32_16x16x32_bf16(af[i], bfr[j], c[i][j], 0,0,0);
        __syncthreads();
    }
    #pragma unroll
    for(int i=0;i<2;i++){
        int mb = n0 + m0 + w*32 + i*16 + lk*4;
        #pragma unroll
        for(int j=0;j<NBF;j++){
            int col = nb0 + j*16 + lm;
            if(gridDim.z == 1){
                #pragma unroll
                for(int r=0;r<4;r++) acc[(size_t)(mb+r)*Co + col] = c[i][j][r];
            } else {
                #pragma unroll
                for(int r=0;r<4;r++) atomicAdd(&acc[(size_t)(mb+r)*Co + col], c[i][j][r]);
            }
        }
    }
}

// ---------------- conv epilogue + fused attention-pool atomics ----------------
__global__ void k_finish2(const float* __restrict__ acc, const int* __restrict__ deg,
        const float* __restrict__ xin, const float* __restrict__ root,
        const float* __restrict__ bias, const float* __restrict__ Wa,
        const float* __restrict__ ba, float* __restrict__ y,
        const int* __restrict__ cl, const float* __restrict__ pin,
        unsigned long long* __restrict__ m_p, float* __restrict__ cntf,
        float* __restrict__ ppos, int N, int Cin, int Co, int NPB){
    extern __shared__ float sm[];
    float* xs  = sm;
    float* red = sm + NPB*Cin;
    int tid = threadIdx.x;
    int nl = tid / Co, co = tid - nl*Co;
    int n = blockIdx.x*NPB + nl;
    bool act = (n < N);
    if(act) for(int c=co; c<Cin; c+=Co) xs[nl*Cin + c] = xin[(size_t)n*Cin + c];
    __syncthreads();
    float yv = 0.f;
    if(act){
        float v = acc[(size_t)n*Co + co] / (float)max(deg[n], 1);
        float rt = 0.f;
        for(int c=0; c<Cin; c++) rt += xs[nl*Cin + c]*root[(size_t)c*Co + co];
        v += rt + bias[co];
        yv = v > 0.f ? v : expm1f(v);
        y[(size_t)n*Co + co] = yv;
    }
    if(m_p){
        float av = act ? yv * Wa[co*2] : 0.f;
        if(Co <= 64){
            #pragma unroll
            for(int off=32; off>0; off>>=1)
                if(off < Co) av += __shfl_xor(av, off, 64);
        } else {
            red[tid] = av;
            __syncthreads();
            int cur = Co;
            while(cur > 1){
                int half = (cur+1) >> 1;
                if(co < cur-half) red[nl*Co+co] += red[nl*Co+co+half];
                __syncthreads();
                cur = half;
            }
            av = red[nl*Co];
        }
        if(act && co==0){
            float attv = av + ba[0];
            int c = cl[n];
            unsigned long long pk = ((unsigned long long)f2ord(attv) << 32) | (unsigned)(~n);
            atomicMax(&m_p[c], pk);
            atomicAdd(&cntf[c], 1.f);
            atomicAdd(&ppos[c*3+0], pin[n*3+0]);
            atomicAdd(&ppos[c*3+1], pin[n*3+1]);
            atomicAdd(&ppos[c*3+2], pin[n*3+2]);
        }
    }
}

// ---------------- pool gather ----------------
__global__ void k_pool3(const unsigned long long* __restrict__ m_p, const float* __restrict__ cntf,
        const float* __restrict__ ppos, const float* __restrict__ x,
        float* __restrict__ xo, float* __restrict__ poso, int nc, int Co, int nmax){
    int t = blockIdx.x*blockDim.x + threadIdx.x;
    if(t >= nc*Co) return;
    int c = t / Co;
    int co = t - c*Co;
    unsigned s = ~(unsigned)(m_p[c] & 0xFFFFFFFFull);
    s = min(s, (unsigned)(nmax-1));
    xo[(size_t)c*Co + co] = x[(size_t)s*Co + co];
    if(co < 3) poso[c*3+co] = ppos[c*3+co] / fmaxf(cntf[c], 1.f);
}

// ---------------- final voxel max pool ----------------
__global__ void k_vox(const float* __restrict__ x, const float* __restrict__ pos,
        unsigned* __restrict__ mx_u, float* __restrict__ cnt8){
    int nidx = blockIdx.x, ch = threadIdx.x;
    int v0 = min(max((int)floorf(pos[nidx*3+0]+0.5f),0),1);
    int v1 = min(max((int)floorf(pos[nidx*3+1]+0.5f),0),1);
    int v2 = min(max((int)floorf(pos[nidx*3+2]+0.5f),0),1);
    int b = nidx >> 3;
    int cl = b*8 + v0*4 + v1*2 + v2;
    atomicMax(&mx_u[cl*256+ch], f2ord(x[nidx*256+ch]));
    if(ch==0) atomicAdd(&cnt8[cl], 1.f);
}

// ---------------- FC + log_softmax ----------------
__global__ __launch_bounds__(256) void k_fc(const unsigned* __restrict__ mx_u,
        const float* __restrict__ cnt8, const float* __restrict__ Wfc,
        const float* __restrict__ bfc, float* __restrict__ out){
    __shared__ float sred[10][256];
    int b = blockIdx.x, tid = threadIdx.x;
    float p[10];
    #pragma unroll
    for(int j=0;j<10;j++) p[j]=0.f;
    for(int idx=tid; idx<2048; idx+=256){
        int v = idx >> 8;
        float val = (cnt8[b*8+v] > 0.f) ? ord2f(mx_u[b*2048+idx]) : 0.f;
        const float* wr = &Wfc[idx*10];
        #pragma unroll
        for(int j=0;j<10;j++) p[j] += val*wr[j];
    }
    #pragma unroll
    for(int j=0;j<10;j++) sred[j][tid]=p[j];
    __syncthreads();
    for(int s=128;s>0;s>>=1){
        if(tid<s){
            #pragma unroll
            for(int j=0;j<10;j++) sred[j][tid]+=sred[j][tid+s];
        }
        __syncthreads();
    }
    if(tid==0){
        float lg[10], mx=-1e30f, se=0.f;
        for(int j=0;j<10;j++){ lg[j]=sred[j][0]+bfc[j]; mx=fmaxf(mx,lg[j]); }
        for(int j=0;j<10;j++) se += expf(lg[j]-mx);
        float lse = mx + logf(se);
        for(int j=0;j<10;j++) out[b*10+j] = lg[j]-lse;
    }
}

extern "C" void kernel_launch(void* const* d_in, const int* in_sizes, int n_in,
                              void* d_out, int out_size, void* d_ws, size_t ws_size,
                              hipStream_t stream){
    const float* x0   = (const float*)d_in[0];
    const float* pos0 = (const float*)d_in[1];
    const float *Wc[5], *rootc[5], *bc[5];
    for(int i=0;i<5;i++){
        Wc[i]    = (const float*)d_in[2+3*i];
        rootc[i] = (const float*)d_in[3+3*i];
        bc[i]    = (const float*)d_in[4+3*i];
    }
    const float *Wa[4], *ba[4];
    for(int i=0;i<4;i++){
        Wa[i] = (const float*)d_in[17+2*i];
        ba[i] = (const float*)d_in[18+2*i];
    }
    const float* Wfc = (const float*)d_in[25];
    const float* bfc = (const float*)d_in[26];
    const int* ei[5]; for(int i=0;i<5;i++) ei[i] = (const int*)d_in[27+i];
    const int* cl[4]; for(int i=0;i<4;i++) cl[i] = (const int*)d_in[32+i];

    const int NPG[5]   = {2048,512,128,32,8};
    const int chans[6] = {1,32,64,96,128,256};
    const float inv2r[5] = {5.f,5.f,4.f,2.f,1.f};
    const int B = 32;
    int Ns[5], Es[5], KdPs[5];
    int totN=0, totWt=0, accTotZ=0, poolTot=0;
    int nodeBase[5], wtBase[5], accOffZ[5], poolOff[4];
    for(int l=0;l<5;l++){
        Ns[l] = B*NPG[l]; Es[l] = Ns[l]*16;
        int Kd = K3*chans[l];
        KdPs[l] = (Kd + 31) & ~31;
        nodeBase[l] = totN; totN += Ns[l];
        wtBase[l] = totWt; totWt += chans[l+1]*KdPs[l];
        if(l >= 1){ accOffZ[l] = accTotZ; accTotZ += Ns[l]*chans[l+1]; }
    }
    for(int l=0;l<4;l++){ poolOff[l] = poolTot; poolTot += Ns[l+1]; }

    size_t off = 0;
    auto alloc = [&](size_t bytes)->void*{
        void* p = (char*)d_ws + off;
        off = (off + bytes + 255) & ~(size_t)255;
        return p;
    };
    // ---- non-zeroed region ----
    float*    x_a    = (float*)   alloc((size_t)65536*32*4);
    float*    x_b    = (float*)   alloc((size_t)16384*32*4);
    float*    pos_a  = (float*)   alloc((size_t)16384*3*4);
    float*    pos_b  = (float*)   alloc((size_t)4096*3*4);
    float*    acc0   = (float*)   alloc((size_t)65536*32*4);   // L1 acc (S==1, no zero)
    int*      slots_a= (int*)     alloc((size_t)totN*64*4);
    unsigned short* Wt_a = (unsigned short*)alloc((size_t)totWt*2);
    // ---- zero region (single memset) ----
    size_t zstart = off;
    int*      cnt_a  = (int*)     alloc((size_t)totN*4);
    float*    accz_a = (float*)   alloc((size_t)accTotZ*4);
    unsigned long long* m_p_a = (unsigned long long*)alloc((size_t)poolTot*8);
    float*    cntf_a = (float*)   alloc((size_t)poolTot*4);
    float*    ppos_a = (float*)   alloc((size_t)poolTot*12);
    unsigned* mx_u   = (unsigned*)alloc((size_t)256*256*4);
    float*    cnt8   = (float*)   alloc((size_t)256*4);
    size_t zlen = off - zstart;
    // ---- A tail ----
    unsigned short* A = (unsigned short*)((char*)d_ws + off);
    size_t Abudget = (ws_size > off) ? (ws_size - off) : 0;

    PreArgs pa;
    int fb = 0, wb = 0;
    for(int l=0;l<5;l++){
        pa.src[l] = ei[l];
        pa.dst[l] = ei[l] + Es[l];
        pa.cnt[l] = cnt_a + nodeBase[l];
        pa.slots[l] = slots_a + (size_t)nodeBase[l]*64;
        pa.E[l] = Es[l];
        pa.W[l] = Wc[l]; pa.Wt[l] = Wt_a + wtBase[l];
        pa.Kd[l] = K3*chans[l]; pa.KdP[l] = KdPs[l]; pa.Co[l] = chans[l+1];
        pa.fillFirst[l] = fb; fb += (Es[l] + 255)/256;
        pa.ktiles[l] = (KdPs[l] + 63)/64;
        pa.wtFirst[l] = wb; wb += pa.ktiles[l] * ((chans[l+1] + 63)/64);
    }
    pa.fillFirst[5] = fb;
    pa.wtFirst[5] = wb;
    int preBlocks = fb + wb;

    hipMemsetAsync((char*)d_ws + zstart, 0, zlen, stream);
    k_pre2<<<preBlocks, 256, 0, stream>>>(pa);

    const float* xin = x0;
    const float* pin = pos0;

    for(int L=0; L<5; L++){
        int N  = Ns[L];
        int Cin = chans[L], Co = chans[L+1];
        int KdP = KdPs[L];
        const int* cntL   = cnt_a + nodeBase[L];
        const int* slotsL = slots_a + (size_t)nodeBase[L]*64;
        const unsigned short* WtL = pa.Wt[L];
        float* accL = (L == 0) ? acc0 : (accz_a + accOffZ[L]);

        size_t nodeb = (size_t)KdP*2;
        int Mc = (int)(Abudget / nodeb);
        Mc = (Mc / 128) * 128;
        if(Mc < 128) Mc = 128;
        if(Mc > N) Mc = N;

        for(int rn0=0; rn0<N; rn0+=Mc){
            int rn1 = (rn0+Mc < N) ? rn0+Mc : N;
            int Mr  = rn1 - rn0;
            if(Cin==1)
                k_build1<<<Mr/32, 256, 0, stream>>>(slotsL, cntL, pin, xin, inv2r[L], rn0, KdP, A);
            else
                k_build2<<<dim3(Mr, Cin/32), 256, 0, stream>>>(slotsL, cntL, pin, xin,
                                                               inv2r[L], rn0, Cin, KdP, A);

            int BN = (Co % 64 == 0) ? 64 : 32;
            int gx = Mr/128, gy = Co/BN;
            int S = 768/(gx*gy);
            if(S < 1) S = 1;
            if(L == 0) S = 1;   // acc0 is not pre-zeroed; must use plain stores
            int maxS = KdP/32;
            if(S > maxS) S = maxS;
            int Kper = ((KdP + S - 1)/S + 31) & ~31;
            S = (KdP + Kper - 1)/Kper;
            dim3 g(gx, gy, S);
            if(BN == 64) k_mfma<64><<<g, 256, 0, stream>>>(A, WtL, accL, rn0, Co, KdP, Kper);
            else         k_mfma<32><<<g, 256, 0, stream>>>(A, WtL, accL, rn0, Co, KdP, Kper);
        }

        float* y = x_a;
        int NPB = 256/Co; if(NPB < 1) NPB = 1;
        int thr = NPB*Co;
        size_t smb = (size_t)(NPB*Cin + NPB*Co)*4;
        bool haspool = (L < 4);
        k_finish2<<<(N+NPB-1)/NPB, thr, smb, stream>>>(accL, cntL, xin, rootc[L], bc[L],
            haspool?Wa[L]:nullptr, haspool?ba[L]:nullptr, y,
            haspool?cl[L]:nullptr, pin,
            haspool?(m_p_a+poolOff[L]):nullptr,
            haspool?(cntf_a+poolOff[L]):nullptr,
            haspool?(ppos_a+(size_t)poolOff[L]*3):nullptr,
            N, Cin, Co, NPB);

        if(haspool){
            int nc = Ns[L+1];
            float* pout = (L%2==0) ? pos_a : pos_b;
            k_pool3<<<(nc*Co+255)/256, 256, 0, stream>>>(m_p_a+poolOff[L], cntf_a+poolOff[L],
                ppos_a+(size_t)poolOff[L]*3, y, x_b, pout, nc, Co, N);
            xin = x_b; pin = pout;
        }
    }

    k_vox<<<256, 256, 0, stream>>>(x_a, pin, mx_u, cnt8);
    k_fc<<<32, 256, 0, stream>>>(mx_u, cnt8, Wfc, bfc, (float*)d_out);
}